// Round 1
// baseline (3526.661 us; speedup 1.0000x reference)
//
#include <hip/hip_runtime.h>

// Dims
// B=16 C=32 N=400 T=12 R=64 G=16 E=64 H=2 DH=32 FE=256
#define TT 12

// ---------------------------------------------------------------------------
// Generic spatial contraction over (b,c) batches:
// out[bc, vo, t] = (base? base + scale*relu?(acc) : acc),
// acc = sum_vi M * in[bc, vi, t];  orientT: M[vi*Vout+vo], else M[vo*Vin+vi]
// ---------------------------------------------------------------------------
__global__ void __launch_bounds__(256) k_spatial(
    const float* __restrict__ M, int orientT, int Vin, int Vout,
    const float* __restrict__ in, const float* __restrict__ base,
    float scale, int do_relu, float* __restrict__ out)
{
    __shared__ float in_lds[400 * TT];
    int bc = blockIdx.x;
    const float* ib = in + (size_t)bc * Vin * TT;
    for (int i = threadIdx.x; i < Vin * TT; i += 256) in_lds[i] = ib[i];
    __syncthreads();
    int tot = Vout * TT;
    size_t obase = (size_t)bc * tot;
    for (int idx = threadIdx.x; idx < tot; idx += 256) {
        int vo = idx / TT, t = idx - vo * TT;
        float acc = 0.f;
        if (orientT) {
            for (int vi = 0; vi < Vin; ++vi)
                acc += M[(size_t)vi * Vout + vo] * in_lds[vi * TT + t];
        } else {
            const float* Mr = M + (size_t)vo * Vin;
            for (int vi = 0; vi < Vin; ++vi)
                acc += Mr[vi] * in_lds[vi * TT + t];
        }
        if (do_relu) acc = fmaxf(acc, 0.f);
        acc *= scale;
        if (base) acc += base[obase + idx];
        out[obase + idx] = acc;
    }
}

// ---------------------------------------------------------------------------
// GCN combine: out[b,o,v,t] = bias[o] + sum_c W[o,c]*x + W[o,32+c]*t0 + W[o,64+c]*t1
// Grid: B * (V/8). LDS layout [s=12v+t][c] stride 33 (bank-conflict-free).
// ---------------------------------------------------------------------------
__global__ void __launch_bounds__(256) k_gcn_combine(
    const float* __restrict__ x, const float* __restrict__ t0in,
    const float* __restrict__ t1in, const float* __restrict__ W,
    const float* __restrict__ bias, int V, float* __restrict__ out)
{
    __shared__ float xs_[96 * 33], t0s[96 * 33], t1s[96 * 33], WT[96 * 32];
    int nb = V / 8;
    int b = blockIdx.x / nb, n0 = (blockIdx.x % nb) * 8;
    for (int l = threadIdx.x; l < 96 * 32; l += 256) {
        int c3 = l >> 5, o = l & 31;
        WT[l] = W[o * 96 + c3];
    }
    for (int l = threadIdx.x; l < 3072; l += 256) {
        int c = l / 96, s = l - c * 96;
        size_t g = ((size_t)((b * 32 + c) * V) + n0 + s / 12) * 12 + (s % 12);
        xs_[s * 33 + c] = x[g];
        t0s[s * 33 + c] = t0in[g];
        t1s[s * 33 + c] = t1in[g];
    }
    __syncthreads();
    for (int idx = threadIdx.x; idx < 3072; idx += 256) {
        int o = idx / 96, s = idx - o * 96;
        float acc = bias[o];
        for (int c = 0; c < 32; ++c) {
            float a = xs_[s * 33 + c] * WT[c * 32 + o];
            float b2 = t0s[s * 33 + c] * WT[(32 + c) * 32 + o];
            float c2 = t1s[s * 33 + c] * WT[(64 + c) * 32 + o];
            acc += a + b2 + c2;
        }
        out[((size_t)(b * 32 + o) * V + n0) * 12 + s] = acc;
    }
}

// ---------------------------------------------------------------------------
// 1x1 conv C->E with layout change (B,C,N,T) -> (B,N,T,E), optional +ds[n,e]
// Grid: B*50 (8 n's per block)
// ---------------------------------------------------------------------------
__global__ void __launch_bounds__(256) k_conv1(
    const float* __restrict__ x, const float* __restrict__ W,
    const float* __restrict__ bias, const float* __restrict__ dsadd,
    float* __restrict__ out)
{
    __shared__ float xs_[96 * 33];
    __shared__ float WT[2048];
    int b = blockIdx.x / 50, n0 = (blockIdx.x % 50) * 8;
    for (int l = threadIdx.x; l < 2048; l += 256) {
        int c = l >> 6, o = l & 63;
        WT[l] = W[o * 32 + c];
    }
    for (int l = threadIdx.x; l < 3072; l += 256) {
        int c = l / 96, s = l - c * 96;
        xs_[s * 33 + c] = x[((size_t)(b * 32 + c) * 400 + n0 + s / 12) * 12 + (s % 12)];
    }
    __syncthreads();
    for (int idx = threadIdx.x; idx < 6144; idx += 256) {
        int s = idx >> 6, o = idx & 63;
        float acc = bias[o];
        for (int c = 0; c < 32; ++c) acc += xs_[s * 33 + c] * WT[(c << 6) + o];
        if (dsadd) acc += dsadd[(n0 + s / 12) * 64 + o];
        out[((size_t)b * 4800 + n0 * 12 + s) * 64 + o] = acc;
    }
}

// ---------------------------------------------------------------------------
// ds[n,e] = sum_m D_S[n,m] * W_embed[e,m] + b_embed[e].  Grid 400, block 64.
// ---------------------------------------------------------------------------
__global__ void __launch_bounds__(64) k_ds(
    const float* __restrict__ D_S, const float* __restrict__ Wem,
    const float* __restrict__ bem, float* __restrict__ ds)
{
    __shared__ float row[400];
    int n = blockIdx.x;
    for (int i = threadIdx.x; i < 400; i += 64) row[i] = D_S[n * 400 + i];
    __syncthreads();
    int e = threadIdx.x;
    float acc = bem[e];
    const float* we = Wem + (size_t)e * 400;
    for (int m = 0; m < 400; ++m) acc += row[m] * we[m];
    ds[n * 64 + e] = acc;
}

// ---------------------------------------------------------------------------
// Ag partial: Ag[g1,g2] += sum_i xs[b1,c1,g1,t1]*xs[b2,c2,g2,t2]
// i decomposed (c,b,t) for the left and (t,b,c) for the right (reference's
// mismatched reshape). Grid 24 x 256 i's.
// ---------------------------------------------------------------------------
__global__ void __launch_bounds__(256) k_agp(const float* __restrict__ xs,
                                             float* __restrict__ Ag)
{
    __shared__ float A[256 * 17], Bv[256 * 17];
    int i = blockIdx.x * 256 + threadIdx.x;  // < 6144
    int c1 = i / 192, b1 = (i / 12) & 15, t1 = i % 12;
    int t2 = i >> 9, b2 = (i >> 5) & 15, c2 = i & 31;
    for (int g = 0; g < 16; ++g) {
        A[threadIdx.x * 17 + g] = xs[((size_t)(b1 * 32 + c1) * 16 + g) * 12 + t1];
        Bv[threadIdx.x * 17 + g] = xs[((size_t)(b2 * 32 + c2) * 16 + g) * 12 + t2];
    }
    __syncthreads();
    int g1 = threadIdx.x >> 4, g2 = threadIdx.x & 15;
    float acc = 0.f;
    for (int k = 0; k < 256; ++k) acc += A[k * 17 + g1] * Bv[k * 17 + g2];
    atomicAdd(&Ag[threadIdx.x], acc);
}

// ---------------------------------------------------------------------------
// Ag -> relu(Ag-0.5) -> sg0 = softmax(asym_adj(A)), sg1 = softmax(asym_adj(A^T))
// ---------------------------------------------------------------------------
__global__ void __launch_bounds__(64) k_agf(const float* __restrict__ Ag,
                                            float* __restrict__ sg0,
                                            float* __restrict__ sg1)
{
    __shared__ float Ar[256], rs[16], cs[16];
    int tid = threadIdx.x;
    for (int l = tid; l < 256; l += 64) Ar[l] = fmaxf(Ag[l] - 0.5f, 0.f);
    __syncthreads();
    if (tid < 16) {
        float r = 0.f, c = 0.f;
        for (int j = 0; j < 16; ++j) { r += Ar[tid * 16 + j]; c += Ar[j * 16 + tid]; }
        rs[tid] = (r > 0.f) ? 1.f / r : 0.f;
        cs[tid] = (c > 0.f) ? 1.f / c : 0.f;
    }
    __syncthreads();
    if (tid < 16) {
        float v[16], m, s;
        m = -1e30f;
        for (int j = 0; j < 16; ++j) { v[j] = Ar[tid * 16 + j] * rs[tid]; m = fmaxf(m, v[j]); }
        s = 0.f;
        for (int j = 0; j < 16; ++j) { v[j] = expf(v[j] - m); s += v[j]; }
        for (int j = 0; j < 16; ++j) sg0[tid * 16 + j] = v[j] / s;
        m = -1e30f;
        for (int j = 0; j < 16; ++j) { v[j] = Ar[j * 16 + tid] * cs[tid]; m = fmaxf(m, v[j]); }
        s = 0.f;
        for (int j = 0; j < 16; ++j) { v[j] = expf(v[j] - m); s += v[j]; }
        for (int j = 0; j < 16; ++j) sg1[tid * 16 + j] = v[j] / s;
    }
}

// ---------------------------------------------------------------------------
// Attention over the node axis. One block per (b,t,h). qq/kk/vv computed
// on the fly from q (B,N,T,E). K^T swizzled stride 401, V row-major in LDS.
// Dynamic LDS = 121728 B.
// ---------------------------------------------------------------------------
__global__ void __launch_bounds__(256) k_attn(
    const float* __restrict__ q, const float* __restrict__ Wq,
    const float* __restrict__ Wk, const float* __restrict__ Wv,
    float* __restrict__ attnO)
{
    extern __shared__ float lds[];
    float* kkT = lds;           // 32*401 = 12832
    float* vvs = kkT + 12832;   // 400*32 = 12800
    float* wqT = vvs + 12800;   // 1024
    float* wkT = wqT + 1024;    // 1024
    float* wvT = wkT + 1024;    // 1024
    float* qrow = wvT + 1024;   // 4*32
    float* pbuf = qrow + 128;   // 4*400

    int bid = blockIdx.x;
    int b = bid / 24, rem = bid % 24, t = rem >> 1, h = rem & 1;
    const float* qbase = q + (size_t)b * 307200 + t * 64 + h * 32;

    for (int l = threadIdx.x; l < 1024; l += 256) {
        int d = l >> 5, e = l & 31;
        wqT[l] = Wq[e * 32 + d];
        wkT[l] = Wk[e * 32 + d];
        wvT[l] = Wv[e * 32 + d];
    }
    __syncthreads();
    for (int l = threadIdx.x; l < 12800; l += 256) {
        int k = l >> 5, e = l & 31;
        const float* qk = qbase + (size_t)k * 768;
        float ak = 0.f, av = 0.f;
        for (int d = 0; d < 32; ++d) {
            float qv = qk[d];
            ak += qv * wkT[d * 32 + e];
            av += qv * wvT[d * 32 + e];
        }
        kkT[e * 401 + k] = ak;
        vvs[k * 32 + e] = av;
    }
    __syncthreads();

    int wave = threadIdx.x >> 6, lane = threadIdx.x & 63;
    for (int it = 0; it < 100; ++it) {
        int row = wave + (it << 2);
        if (lane < 32) {
            const float* qr = qbase + (size_t)row * 768;
            float a = 0.f;
            for (int d = 0; d < 32; ++d) a += qr[d] * wqT[d * 32 + lane];
            qrow[wave * 32 + lane] = a;
        }
        __syncthreads();
        float ev[7];
        float m = -1e30f;
        for (int j = 0; j < 7; ++j) {
            int k = lane + (j << 6);
            if (k < 400) {
                float a = 0.f;
                for (int d = 0; d < 32; ++d) a += qrow[wave * 32 + d] * kkT[d * 401 + k];
                a *= 0.125f;  // / sqrt(E)
                ev[j] = a;
                m = fmaxf(m, a);
            } else ev[j] = -1e30f;
        }
        for (int off = 32; off; off >>= 1) m = fmaxf(m, __shfl_xor(m, off));
        float s = 0.f;
        for (int j = 0; j < 7; ++j) {
            int k = lane + (j << 6);
            if (k < 400) {
                float p = expf(ev[j] - m);
                pbuf[wave * 400 + k] = p;
                s += p;
            }
        }
        for (int off = 32; off; off >>= 1) s += __shfl_xor(s, off);
        __syncthreads();
        int half = lane >> 5, d = lane & 31;
        float acc = 0.f;
        const float* pb = pbuf + wave * 400 + half * 200;
        const float* vb = vvs + half * 200 * 32 + d;
        for (int k = 0; k < 200; ++k) acc += pb[k] * vb[k * 32];
        acc += __shfl_down(acc, 32);
        if (lane < 32)
            attnO[(size_t)b * 307200 + (size_t)row * 768 + t * 64 + h * 32 + d] = acc / s;
        __syncthreads();
    }
}

// ---------------------------------------------------------------------------
// A1: x = LN(attnO @ Wfc^T + bfc + q) per row; 32 rows/block; wave = row
// ---------------------------------------------------------------------------
__global__ void __launch_bounds__(256) k_A1(
    const float* __restrict__ attnO, const float* __restrict__ Wfc,
    const float* __restrict__ bfc, const float* __restrict__ qbuf,
    const float* __restrict__ w1, const float* __restrict__ b1,
    float* __restrict__ xout)
{
    __shared__ float WT[4096], ao[2048], qs[2048];
    size_t r0 = (size_t)blockIdx.x * 32;
    for (int l = threadIdx.x; l < 4096; l += 256) {
        int e = l >> 6, o = l & 63;
        WT[l] = Wfc[o * 64 + e];
    }
    for (int l = threadIdx.x; l < 2048; l += 256) {
        ao[l] = attnO[r0 * 64 + l];
        qs[l] = qbuf[r0 * 64 + l];
    }
    __syncthreads();
    int o = threadIdx.x & 63, w = threadIdx.x >> 6;
    for (int k = 0; k < 8; ++k) {
        int r = w + (k << 2);
        float acc = bfc[o];
        for (int e = 0; e < 64; ++e) acc += ao[r * 64 + e] * WT[e * 64 + o];
        float val = acc + qs[r * 64 + o];
        float sum = val;
        for (int off = 32; off; off >>= 1) sum += __shfl_xor(sum, off);
        float mean = sum * (1.f / 64.f);
        float dv = val - mean;
        float vs = dv * dv;
        for (int off = 32; off; off >>= 1) vs += __shfl_xor(vs, off);
        float inv = rsqrtf(vs * (1.f / 64.f) + 1e-5f);
        xout[(r0 + r) * 64 + o] = dv * inv * w1[o] + b1[o];
    }
}

// ---------------------------------------------------------------------------
// A2 fused FF: US = LN(relu(x@W1^T+b1)@W2^T+b2 + x). 16 rows/block.
// Dynamic LDS 151552 B (x 4KB + W1T 64KB + W2T 64KB + ffh 16KB)
// ---------------------------------------------------------------------------
__global__ void __launch_bounds__(256) k_A2(
    const float* __restrict__ xin, const float* __restrict__ Wff1,
    const float* __restrict__ bff1, const float* __restrict__ Wff2,
    const float* __restrict__ bff2, const float* __restrict__ w2,
    const float* __restrict__ b2, float* __restrict__ US)
{
    extern __shared__ float lds[];
    float* xs_ = lds;            // 1024
    float* W1T = xs_ + 1024;     // 16384
    float* W2T = W1T + 16384;    // 16384
    float* fh = W2T + 16384;     // 4096
    size_t r0 = (size_t)blockIdx.x * 16;
    for (int l = threadIdx.x; l < 1024; l += 256) xs_[l] = xin[r0 * 64 + l];
    for (int l = threadIdx.x; l < 16384; l += 256) {
        int e = l >> 8, f = l & 255;
        W1T[l] = Wff1[f * 64 + e];
        int f2 = l >> 6, o = l & 63;
        W2T[l] = Wff2[o * 256 + f2];
    }
    __syncthreads();
    int lane = threadIdx.x & 63, w = threadIdx.x >> 6;
    for (int k = 0; k < 4; ++k) {
        int r = w + (k << 2);
        for (int j = 0; j < 4; ++j) {
            int f = lane + (j << 6);
            float acc = bff1[f];
            for (int e = 0; e < 64; ++e) acc += xs_[r * 64 + e] * W1T[e * 256 + f];
            fh[r * 256 + f] = fmaxf(acc, 0.f);
        }
    }
    __syncthreads();
    for (int k = 0; k < 4; ++k) {
        int r = w + (k << 2);
        float acc = bff2[lane];
        for (int f = 0; f < 256; ++f) acc += fh[r * 256 + f] * W2T[f * 64 + lane];
        float val = acc + xs_[r * 64 + lane];
        float sum = val;
        for (int off = 32; off; off >>= 1) sum += __shfl_xor(sum, off);
        float mean = sum * (1.f / 64.f);
        float dv = val - mean;
        float vs = dv * dv;
        for (int off = 32; off; off >>= 1) vs += __shfl_xor(vs, off);
        float inv = rsqrtf(vs * (1.f / 64.f) + 1e-5f);
        US[(r0 + r) * 64 + lane] = dv * inv * w2[lane] + b2[lane];
    }
}

// ---------------------------------------------------------------------------
// A3: gate + blend + final 1x1 conv E->C with transpose to (B,C,N,T).
// 16 rows/block.
// ---------------------------------------------------------------------------
__global__ void __launch_bounds__(256) k_A3(
    const float* __restrict__ US, const float* __restrict__ Xc,
    const float* __restrict__ Wfs, const float* __restrict__ bfs,
    const float* __restrict__ Wfg, const float* __restrict__ bfg,
    const float* __restrict__ Wc11, const float* __restrict__ bc11,
    float* __restrict__ out)
{
    __shared__ float us[1024], xc[1024], WsT[4096], WgT[4096], WcT[2048], op[16 * 65];
    size_t R0 = (size_t)blockIdx.x * 16;
    for (int l = threadIdx.x; l < 4096; l += 256) {
        int e = l >> 6, o = l & 63;
        WsT[l] = Wfs[o * 64 + e];
        WgT[l] = Wfg[o * 64 + e];
    }
    for (int l = threadIdx.x; l < 2048; l += 256) {
        int e = l >> 5, oc = l & 31;
        WcT[l] = Wc11[oc * 64 + e];
    }
    for (int l = threadIdx.x; l < 1024; l += 256) {
        us[l] = US[R0 * 64 + l];
        xc[l] = Xc[R0 * 64 + l];
    }
    __syncthreads();
    int o = threadIdx.x & 63, w = threadIdx.x >> 6;
    for (int k = 0; k < 4; ++k) {
        int r = w + (k << 2);
        float a1 = bfs[o], a2 = bfg[o];
        for (int e = 0; e < 64; ++e) {
            a1 += us[r * 64 + e] * WsT[e * 64 + o];
            a2 += xc[r * 64 + e] * WgT[e * 64 + o];
        }
        float g = 1.f / (1.f + expf(-(a1 + a2)));
        op[r * 65 + o] = g * us[r * 64 + o] + (1.f - g) * xc[r * 64 + o];
    }
    __syncthreads();
    int b = (int)(R0 / 4800);
    int rr = (int)(R0 % 4800);
    for (int k2 = 0; k2 < 2; ++k2) {
        int idx = threadIdx.x + (k2 << 8);
        int rloc = idx & 15, oc = idx >> 4;
        float acc = bc11[oc];
        for (int e = 0; e < 64; ++e) acc += op[rloc * 65 + e] * WcT[e * 32 + oc];
        out[(size_t)(b * 32 + oc) * 4800 + rr + rloc] = acc;
    }
}

// ---------------------------------------------------------------------------
extern "C" void kernel_launch(void* const* d_in, const int* in_sizes, int n_in,
                              void* d_out, int out_size, void* d_ws, size_t ws_size,
                              hipStream_t stream)
{
    (void)in_sizes; (void)n_in; (void)out_size; (void)ws_size;
    const float* query = (const float*)d_in[2];
    const float* s0    = (const float*)d_in[3];
    const float* s1    = (const float*)d_in[4];
    const float* sr0   = (const float*)d_in[5];
    const float* sr1   = (const float*)d_in[6];
    const float* Mrg   = (const float*)d_in[7];
    const float* Mor   = (const float*)d_in[8];
    const float* D_S   = (const float*)d_in[9];
    const float* Wc1   = (const float*)d_in[10];
    const float* bc1   = (const float*)d_in[11];
    const float* Wc11  = (const float*)d_in[12];
    const float* bc11  = (const float*)d_in[13];
    const float* Wg    = (const float*)d_in[14];
    const float* bg    = (const float*)d_in[15];
    const float* Wem   = (const float*)d_in[16];
    const float* bem   = (const float*)d_in[17];
    const float* Wq    = (const float*)d_in[18];
    const float* Wk    = (const float*)d_in[19];
    const float* Wv    = (const float*)d_in[20];
    const float* Wfc   = (const float*)d_in[21];
    const float* bfc   = (const float*)d_in[22];
    const float* ln1w  = (const float*)d_in[23];
    const float* ln1b  = (const float*)d_in[24];
    const float* ln2w  = (const float*)d_in[25];
    const float* ln2b  = (const float*)d_in[26];
    const float* Wff1  = (const float*)d_in[27];
    const float* bff1  = (const float*)d_in[28];
    const float* Wff2  = (const float*)d_in[29];
    const float* bff2  = (const float*)d_in[30];
    const float* Wfs   = (const float*)d_in[31];
    const float* bfs   = (const float*)d_in[32];
    const float* Wfg   = (const float*)d_in[33];
    const float* bfg   = (const float*)d_in[34];

    float* ws = (float*)d_ws;
    size_t off = 0;
    auto alloc = [&](size_t n) { float* p = ws + off; off += n; return p; };
    float* q_buf = alloc(4915200);   // (B,N,T,E)
    float* Xc    = alloc(4915200);   // (B,N,T,E)
    float* x_buf = alloc(4915200);
    float* US    = alloc(4915200);
    float* ho    = alloc(2457600);   // (B,C,N,T)
    float* t0    = alloc(2457600);
    float* t1    = alloc(2457600);
    float* attnO = t0;               // alias: t0+t1 (4915200) free after combine
    float* xr    = alloc(393216);    // (B,C,R,T)
    float* tr0   = alloc(393216);
    float* tr1   = alloc(393216);
    float* hr    = alloc(393216);
    float* xsg   = alloc(98304);     // (B,C,G,T)
    float* tg0   = alloc(98304);
    float* tg1   = alloc(98304);
    float* xg0   = alloc(98304);
    float* dsb   = alloc(25600);     // (N,E)
    float* Ag    = alloc(256);
    float* sg0   = alloc(256);
    float* sg1   = alloc(256);

    float* out_main = (float*)d_out;          // (B,C,N,T)
    float* out_xc   = out_main + 2457600;     // (B,C,R,T) final hr
    float* out_xs   = out_main + 2850816;     // (B,C,G,T) final xg

    hipFuncSetAttribute((const void*)k_attn,
                        hipFuncAttributeMaxDynamicSharedMemorySize, 121728);
    hipFuncSetAttribute((const void*)k_A2,
                        hipFuncAttributeMaxDynamicSharedMemorySize, 151552);

    hipMemsetAsync(Ag, 0, 256 * sizeof(float), stream);

    // ---- CHGCN ----
    k_spatial<<<512, 256, 0, stream>>>(s0, 1, 400, 400, query, nullptr, 1.f, 0, t0);
    k_spatial<<<512, 256, 0, stream>>>(s1, 1, 400, 400, query, nullptr, 1.f, 0, t1);
    k_gcn_combine<<<800, 256, 0, stream>>>(query, t0, t1, Wg, bg, 400, ho);
    k_spatial<<<512, 256, 0, stream>>>(Mor, 1, 400, 64, query, nullptr, 1.f, 0, xr);
    k_spatial<<<512, 256, 0, stream>>>(sr0, 1, 64, 64, xr, nullptr, 1.f, 0, tr0);
    k_spatial<<<512, 256, 0, stream>>>(sr1, 1, 64, 64, xr, nullptr, 1.f, 0, tr1);
    k_gcn_combine<<<128, 256, 0, stream>>>(xr, tr0, tr1, Wg, bg, 64, hr);
    k_spatial<<<512, 256, 0, stream>>>(Mrg, 1, 64, 16, xr, nullptr, 1.f, 0, xsg);
    k_agp<<<24, 256, 0, stream>>>(xsg, Ag);
    k_agf<<<1, 64, 0, stream>>>(Ag, sg0, sg1);
    k_spatial<<<512, 256, 0, stream>>>(sg0, 1, 16, 16, xsg, nullptr, 1.f, 0, tg0);
    k_spatial<<<512, 256, 0, stream>>>(sg1, 1, 16, 16, xsg, nullptr, 1.f, 0, tg1);
    k_gcn_combine<<<32, 256, 0, stream>>>(xsg, tg0, tg1, Wg, bg, 16, xg0);
    k_spatial<<<512, 256, 0, stream>>>(Mrg, 0, 16, 64, xg0, hr, 0.5f, 1, hr);
    k_spatial<<<512, 256, 0, stream>>>(Mor, 0, 64, 400, hr, ho, 0.5f, 1, ho);
    k_spatial<<<512, 256, 0, stream>>>(Mor, 1, 400, 64, ho, hr, 0.5f, 1, out_xc);
    k_spatial<<<512, 256, 0, stream>>>(Mrg, 1, 64, 16, out_xc, xg0, 0.5f, 1, out_xs);

    // ---- Transformer front ----
    k_ds<<<400, 64, 0, stream>>>(D_S, Wem, bem, dsb);
    k_conv1<<<800, 256, 0, stream>>>(ho, Wc1, bc1, nullptr, Xc);
    k_conv1<<<800, 256, 0, stream>>>(query, Wc1, bc1, dsb, q_buf);
    k_attn<<<384, 256, 121728, stream>>>(q_buf, Wq, Wk, Wv, attnO);
    k_A1<<<2400, 256, 0, stream>>>(attnO, Wfc, bfc, q_buf, ln1w, ln1b, x_buf);
    k_A2<<<4800, 256, 151552, stream>>>(x_buf, Wff1, bff1, Wff2, bff2, ln2w, ln2b, US);
    k_A3<<<4800, 256, 0, stream>>>(US, Xc, Wfs, bfs, Wfg, bfg, Wc11, bc11, out_main);
}

// Round 2
// 2065.515 us; speedup vs baseline: 1.7074x; 1.7074x over previous
//
#include <hip/hip_runtime.h>

// Dims: B=16 C=32 N=400 T=12 R=64 G=16 E=64 H=2 DH=32 FE=256
#define TT 12

// ---------------------------------------------------------------------------
// Generic spatial contraction over (b,c) batches, vo-chunked via blockIdx.y:
// out[bc, vo, t] = base? base + scale*relu?(acc) : acc
// acc = sum_vi M * in[bc, vi, t]; orientT: M[vi*Vout+vo], else M[vo*Vin+vi]
// ---------------------------------------------------------------------------
__global__ void __launch_bounds__(256) k_spatial(
    const float* __restrict__ M, int orientT, int Vin, int Vout,
    const float* __restrict__ in, const float* __restrict__ base,
    float scale, int do_relu, float* __restrict__ out)
{
    __shared__ float in_lds[400 * TT];
    int bc = blockIdx.x;
    const float* ib = in + (size_t)bc * Vin * TT;
    for (int i = threadIdx.x; i < Vin * TT; i += 256) in_lds[i] = ib[i];
    __syncthreads();
    int chunk = Vout / gridDim.y;
    int vo0 = blockIdx.y * chunk;
    size_t obase = (size_t)bc * Vout * TT;
    for (int idx = threadIdx.x; idx < chunk * TT; idx += 256) {
        int vo = vo0 + idx / TT, t = idx - (idx / TT) * TT;
        float acc = 0.f;
        if (orientT) {
            for (int vi = 0; vi < Vin; ++vi)
                acc += M[(size_t)vi * Vout + vo] * in_lds[vi * TT + t];
        } else {
            const float* Mr = M + (size_t)vo * Vin;
            for (int vi = 0; vi < Vin; ++vi)
                acc += Mr[vi] * in_lds[vi * TT + t];
        }
        if (do_relu) acc = fmaxf(acc, 0.f);
        acc *= scale;
        size_t oi = obase + (size_t)vo * TT + t;
        if (base) acc += base[oi];
        out[oi] = acc;
    }
}

// ---------------------------------------------------------------------------
// GCN combine: out[b,o,v,t] = bias[o] + sum_c W[o,c]*x + W[o,32+c]*t0 + W[o,64+c]*t1
// ---------------------------------------------------------------------------
__global__ void __launch_bounds__(256) k_gcn_combine(
    const float* __restrict__ x, const float* __restrict__ t0in,
    const float* __restrict__ t1in, const float* __restrict__ W,
    const float* __restrict__ bias, int V, float* __restrict__ out)
{
    __shared__ float xs_[96 * 33], t0s[96 * 33], t1s[96 * 33], WT[96 * 32];
    int nb = V / 8;
    int b = blockIdx.x / nb, n0 = (blockIdx.x % nb) * 8;
    for (int l = threadIdx.x; l < 96 * 32; l += 256) {
        int c3 = l >> 5, o = l & 31;
        WT[l] = W[o * 96 + c3];
    }
    for (int l = threadIdx.x; l < 3072; l += 256) {
        int c = l / 96, s = l - c * 96;
        size_t g = ((size_t)((b * 32 + c) * V) + n0 + s / 12) * 12 + (s % 12);
        xs_[s * 33 + c] = x[g];
        t0s[s * 33 + c] = t0in[g];
        t1s[s * 33 + c] = t1in[g];
    }
    __syncthreads();
    for (int idx = threadIdx.x; idx < 3072; idx += 256) {
        int o = idx / 96, s = idx - o * 96;
        float acc = bias[o];
        for (int c = 0; c < 32; ++c) {
            float a = xs_[s * 33 + c] * WT[c * 32 + o];
            float b2 = t0s[s * 33 + c] * WT[(32 + c) * 32 + o];
            float c2 = t1s[s * 33 + c] * WT[(64 + c) * 32 + o];
            acc += a + b2 + c2;
        }
        out[((size_t)(b * 32 + o) * V + n0) * 12 + s] = acc;
    }
}

// ---------------------------------------------------------------------------
// 1x1 conv C->E with layout change (B,C,N,T) -> (B,N,T,E), optional +ds[n,e]
// ---------------------------------------------------------------------------
__global__ void __launch_bounds__(256) k_conv1(
    const float* __restrict__ x, const float* __restrict__ W,
    const float* __restrict__ bias, const float* __restrict__ dsadd,
    float* __restrict__ out)
{
    __shared__ float xs_[96 * 33];
    __shared__ float WT[2048];
    int b = blockIdx.x / 50, n0 = (blockIdx.x % 50) * 8;
    for (int l = threadIdx.x; l < 2048; l += 256) {
        int c = l >> 6, o = l & 63;
        WT[l] = W[o * 32 + c];
    }
    for (int l = threadIdx.x; l < 3072; l += 256) {
        int c = l / 96, s = l - c * 96;
        xs_[s * 33 + c] = x[((size_t)(b * 32 + c) * 400 + n0 + s / 12) * 12 + (s % 12)];
    }
    __syncthreads();
    for (int idx = threadIdx.x; idx < 6144; idx += 256) {
        int s = idx >> 6, o = idx & 63;
        float acc = bias[o];
        for (int c = 0; c < 32; ++c) acc += xs_[s * 33 + c] * WT[(c << 6) + o];
        if (dsadd) acc += dsadd[(n0 + s / 12) * 64 + o];
        out[((size_t)b * 4800 + n0 * 12 + s) * 64 + o] = acc;
    }
}

// ---------------------------------------------------------------------------
// ds[n,e] = sum_m D_S[n,m] * W_embed[e,m] + b_embed[e]
// ---------------------------------------------------------------------------
__global__ void __launch_bounds__(64) k_ds(
    const float* __restrict__ D_S, const float* __restrict__ Wem,
    const float* __restrict__ bem, float* __restrict__ ds)
{
    __shared__ float row[400];
    int n = blockIdx.x;
    for (int i = threadIdx.x; i < 400; i += 64) row[i] = D_S[n * 400 + i];
    __syncthreads();
    int e = threadIdx.x;
    float acc = bem[e];
    const float* we = Wem + (size_t)e * 400;
    for (int m = 0; m < 400; ++m) acc += row[m] * we[m];
    ds[n * 64 + e] = acc;
}

// ---------------------------------------------------------------------------
// Ag partial (reference's mismatched reshape contraction)
// ---------------------------------------------------------------------------
__global__ void __launch_bounds__(256) k_agp(const float* __restrict__ xs,
                                             float* __restrict__ Ag)
{
    __shared__ float A[256 * 17], Bv[256 * 17];
    int i = blockIdx.x * 256 + threadIdx.x;  // < 6144
    int c1 = i / 192, b1 = (i / 12) & 15, t1 = i % 12;
    int t2 = i >> 9, b2 = (i >> 5) & 15, c2 = i & 31;
    for (int g = 0; g < 16; ++g) {
        A[threadIdx.x * 17 + g] = xs[((size_t)(b1 * 32 + c1) * 16 + g) * 12 + t1];
        Bv[threadIdx.x * 17 + g] = xs[((size_t)(b2 * 32 + c2) * 16 + g) * 12 + t2];
    }
    __syncthreads();
    int g1 = threadIdx.x >> 4, g2 = threadIdx.x & 15;
    float acc = 0.f;
    for (int k = 0; k < 256; ++k) acc += A[k * 17 + g1] * Bv[k * 17 + g2];
    atomicAdd(&Ag[threadIdx.x], acc);
}

// ---------------------------------------------------------------------------
// Ag -> relu(Ag-0.5) -> sg0/sg1 softmax(asym_adj)
// ---------------------------------------------------------------------------
__global__ void __launch_bounds__(64) k_agf(const float* __restrict__ Ag,
                                            float* __restrict__ sg0,
                                            float* __restrict__ sg1)
{
    __shared__ float Ar[256], rs[16], cs[16];
    int tid = threadIdx.x;
    for (int l = tid; l < 256; l += 64) Ar[l] = fmaxf(Ag[l] - 0.5f, 0.f);
    __syncthreads();
    if (tid < 16) {
        float r = 0.f, c = 0.f;
        for (int j = 0; j < 16; ++j) { r += Ar[tid * 16 + j]; c += Ar[j * 16 + tid]; }
        rs[tid] = (r > 0.f) ? 1.f / r : 0.f;
        cs[tid] = (c > 0.f) ? 1.f / c : 0.f;
    }
    __syncthreads();
    if (tid < 16) {
        float v[16], m, s;
        m = -1e30f;
        for (int j = 0; j < 16; ++j) { v[j] = Ar[tid * 16 + j] * rs[tid]; m = fmaxf(m, v[j]); }
        s = 0.f;
        for (int j = 0; j < 16; ++j) { v[j] = expf(v[j] - m); s += v[j]; }
        for (int j = 0; j < 16; ++j) sg0[tid * 16 + j] = v[j] / s;
        m = -1e30f;
        for (int j = 0; j < 16; ++j) { v[j] = Ar[j * 16 + tid] * cs[tid]; m = fmaxf(m, v[j]); }
        s = 0.f;
        for (int j = 0; j < 16; ++j) { v[j] = expf(v[j] - m); s += v[j]; }
        for (int j = 0; j < 16; ++j) sg1[tid * 16 + j] = v[j] / s;
    }
}

// ---------------------------------------------------------------------------
// QKV projection: qq/kk/vv[g][n][d] = sum_dd q[b,n,t,h*32+dd]*W{q,k,v}[d][dd]
// g = b*24 + t*2 + h. Grid (384, 7), block 256 (64-row tiles).
// ---------------------------------------------------------------------------
__global__ void __launch_bounds__(256) k_qkv(
    const float* __restrict__ q, const float* __restrict__ Wq,
    const float* __restrict__ Wk, const float* __restrict__ Wv,
    float* __restrict__ qq, float* __restrict__ kk, float* __restrict__ vv)
{
    __shared__ float qs[64 * 33], wqT[1024], wkT[1024], wvT[1024];
    int g = blockIdx.x, n0 = blockIdx.y * 64;
    int b = g / 24, rem = g % 24, t = rem >> 1, h = rem & 1;
    int tid = threadIdx.x;
    for (int i = tid; i < 1024; i += 256) {
        int dd = i >> 5, e = i & 31;
        wqT[i] = Wq[e * 32 + dd];
        wkT[i] = Wk[e * 32 + dd];
        wvT[i] = Wv[e * 32 + dd];
    }
    for (int i = tid; i < 2048; i += 256) {
        int n = i >> 5, dd = i & 31;
        int gn = n0 + n;
        qs[n * 33 + dd] = (gn < 400)
            ? q[((size_t)b * 4800 + gn * 12 + t) * 64 + h * 32 + dd] : 0.f;
    }
    __syncthreads();
    int e = tid & 31, ng = tid >> 5;
    float aq[8], ak[8], av[8];
    #pragma unroll
    for (int k = 0; k < 8; ++k) { aq[k] = 0.f; ak[k] = 0.f; av[k] = 0.f; }
    for (int dd = 0; dd < 32; ++dd) {
        float wq = wqT[dd * 32 + e], wk = wkT[dd * 32 + e], wv = wvT[dd * 32 + e];
        #pragma unroll
        for (int k = 0; k < 8; ++k) {
            float xv = qs[(ng + 8 * k) * 33 + dd];
            aq[k] += xv * wq; ak[k] += xv * wk; av[k] += xv * wv;
        }
    }
    #pragma unroll
    for (int k = 0; k < 8; ++k) {
        int gn = n0 + ng + 8 * k;
        if (gn < 400) {
            size_t a = ((size_t)g * 400 + gn) * 32 + e;
            qq[a] = aq[k]; kk[a] = ak[k]; vv[a] = av[k];
        }
    }
}

// ---------------------------------------------------------------------------
// Attention over nodes. Grid 768 = (b,t,h)x2 row-halves; 512 thr = 8 waves.
// Barrier-free row loop: each wave register-tiles 4 q-rows.
// Dyn LDS: kkT 32x449 (zero-padded keys 400..447) + vv 400x32 + pbuf 8x1600
// = 39968 floats = 159872 B.
// ---------------------------------------------------------------------------
__global__ void __launch_bounds__(512) k_attn2(
    const float* __restrict__ qq, const float* __restrict__ kk,
    const float* __restrict__ vv, float* __restrict__ attnO)
{
    extern __shared__ float lds[];
    float* kkT = lds;             // 32*449
    float* vvs = kkT + 14368;     // 400*32
    float* pbuf = vvs + 12800;    // 8 waves * 4*400

    int g = blockIdx.x >> 1, rh = blockIdx.x & 1;
    const float* qq_g = qq + (size_t)g * 12800;
    const float* kk_g = kk + (size_t)g * 12800;
    const float* vv_g = vv + (size_t)g * 12800;
    int tid = threadIdx.x;

    for (int i = tid; i < 1568; i += 512) {          // zero pad cols 400..448
        int d = i / 49, c = i - d * 49;
        kkT[d * 449 + 400 + c] = 0.f;
    }
    for (int i = tid; i < 12800; i += 512) {
        int k = i >> 5, d = i & 31;
        kkT[d * 449 + k] = kk_g[i];
        vvs[i] = vv_g[i];
    }
    __syncthreads();

    int w = tid >> 6, l = tid & 63;
    float* pw = pbuf + w * 1600;
    int b = g / 24, rem = g % 24, t = rem >> 1, h = rem & 1;
    size_t obase = ((size_t)b * 4800 + t) * 64 + h * 32;

    for (int r0 = rh * 200 + w * 4; r0 < rh * 200 + 200; r0 += 32) {
        float e[4][7];
        #pragma unroll
        for (int ri = 0; ri < 4; ++ri)
            #pragma unroll
            for (int j = 0; j < 7; ++j) e[ri][j] = 0.f;

        for (int db = 0; db < 4; ++db) {
            float qreg[4][8];
            #pragma unroll
            for (int ri = 0; ri < 4; ++ri)
                #pragma unroll
                for (int dd = 0; dd < 8; ++dd)
                    qreg[ri][dd] = qq_g[(r0 + ri) * 32 + db * 8 + dd];
            #pragma unroll
            for (int j = 0; j < 7; ++j) {
                #pragma unroll
                for (int dd = 0; dd < 8; ++dd) {
                    float kv = kkT[(db * 8 + dd) * 449 + j * 64 + l];
                    e[0][j] += qreg[0][dd] * kv;
                    e[1][j] += qreg[1][dd] * kv;
                    e[2][j] += qreg[2][dd] * kv;
                    e[3][j] += qreg[3][dd] * kv;
                }
            }
        }
        bool ok6 = (l < 16);
        float s[4];
        #pragma unroll
        for (int ri = 0; ri < 4; ++ri) {
            if (!ok6) e[ri][6] = -1e30f;
            float m = e[ri][0];
            #pragma unroll
            for (int j = 1; j < 7; ++j) m = fmaxf(m, e[ri][j]);
            #pragma unroll
            for (int off = 32; off; off >>= 1) m = fmaxf(m, __shfl_xor(m, off));
            float ss = 0.f;
            #pragma unroll
            for (int j = 0; j < 7; ++j) {
                e[ri][j] = __expf((e[ri][j] - m) * 0.125f);
                ss += e[ri][j];
            }
            #pragma unroll
            for (int off = 32; off; off >>= 1) ss += __shfl_xor(ss, off);
            s[ri] = ss;
            #pragma unroll
            for (int j = 0; j < 6; ++j) pw[ri * 400 + j * 64 + l] = e[ri][j];
            if (ok6) pw[ri * 400 + 384 + l] = e[ri][6];
        }
        asm volatile("" ::: "memory");   // wave-private LDS: in-order DS pipe

        int hh = l >> 5, d = l & 31;
        float o0 = 0.f, o1 = 0.f, o2 = 0.f, o3 = 0.f;
        int kb0 = hh * 200;
        for (int kb = 0; kb < 200; kb += 4) {
            int k = kb0 + kb;
            float4 p0 = *(const float4*)(pw + 0 * 400 + k);
            float4 p1 = *(const float4*)(pw + 1 * 400 + k);
            float4 p2 = *(const float4*)(pw + 2 * 400 + k);
            float4 p3 = *(const float4*)(pw + 3 * 400 + k);
            float v0 = vvs[(k + 0) * 32 + d];
            float v1 = vvs[(k + 1) * 32 + d];
            float v2 = vvs[(k + 2) * 32 + d];
            float v3 = vvs[(k + 3) * 32 + d];
            o0 += p0.x * v0 + p0.y * v1 + p0.z * v2 + p0.w * v3;
            o1 += p1.x * v0 + p1.y * v1 + p1.z * v2 + p1.w * v3;
            o2 += p2.x * v0 + p2.y * v1 + p2.z * v2 + p2.w * v3;
            o3 += p3.x * v0 + p3.y * v1 + p3.z * v2 + p3.w * v3;
        }
        asm volatile("" ::: "memory");
        o0 += __shfl_down(o0, 32);
        o1 += __shfl_down(o1, 32);
        o2 += __shfl_down(o2, 32);
        o3 += __shfl_down(o3, 32);
        if (l < 32) {
            attnO[obase + (size_t)(r0 + 0) * 768 + d] = o0 / s[0];
            attnO[obase + (size_t)(r0 + 1) * 768 + d] = o1 / s[1];
            attnO[obase + (size_t)(r0 + 2) * 768 + d] = o2 / s[2];
            attnO[obase + (size_t)(r0 + 3) * 768 + d] = o3 / s[3];
        }
    }
}

// ---------------------------------------------------------------------------
// A1: x = LN(attnO @ Wfc^T + bfc + q); 32 rows/block (in-place safe per block)
// ---------------------------------------------------------------------------
__global__ void __launch_bounds__(256) k_A1(
    const float* __restrict__ attnO, const float* __restrict__ Wfc,
    const float* __restrict__ bfc, const float* __restrict__ qbuf,
    const float* __restrict__ w1, const float* __restrict__ b1,
    float* __restrict__ xout)
{
    __shared__ float WT[4096], ao[2048], qs[2048];
    size_t r0 = (size_t)blockIdx.x * 32;
    for (int l = threadIdx.x; l < 4096; l += 256) {
        int e = l >> 6, o = l & 63;
        WT[l] = Wfc[o * 64 + e];
    }
    for (int l = threadIdx.x; l < 2048; l += 256) {
        ao[l] = attnO[r0 * 64 + l];
        qs[l] = qbuf[r0 * 64 + l];
    }
    __syncthreads();
    int o = threadIdx.x & 63, w = threadIdx.x >> 6;
    for (int k = 0; k < 8; ++k) {
        int r = w + (k << 2);
        float acc = bfc[o];
        for (int e = 0; e < 64; ++e) acc += ao[r * 64 + e] * WT[e * 64 + o];
        float val = acc + qs[r * 64 + o];
        float sum = val;
        for (int off = 32; off; off >>= 1) sum += __shfl_xor(sum, off);
        float mean = sum * (1.f / 64.f);
        float dv = val - mean;
        float vs = dv * dv;
        for (int off = 32; off; off >>= 1) vs += __shfl_xor(vs, off);
        float inv = rsqrtf(vs * (1.f / 64.f) + 1e-5f);
        xout[(r0 + r) * 64 + o] = dv * inv * w1[o] + b1[o];
    }
}

// ---------------------------------------------------------------------------
// A2 fused FF: US = LN(relu(x@W1^T+b1)@W2^T+b2 + x). 64 rows/block, 512 thr.
// Dyn LDS: xs 64x65 + Wbuf 16384 + fhT 256x65 = 37184 floats = 148736 B
// ---------------------------------------------------------------------------
__global__ void __launch_bounds__(512) k_A2n(
    const float* __restrict__ xin, const float* __restrict__ Wff1,
    const float* __restrict__ bff1, const float* __restrict__ Wff2,
    const float* __restrict__ bff2, const float* __restrict__ w2,
    const float* __restrict__ b2, float* __restrict__ US)
{
    extern __shared__ float lds[];
    float* xs = lds;             // 64*65 = 4160
    float* Wb = xs + 4160;       // 16384
    float* fhT = Wb + 16384;     // 256*65 = 16640
    size_t R0 = (size_t)blockIdx.x * 64;
    int tid = threadIdx.x;
    for (int i = tid; i < 4096; i += 512) {
        int r = i >> 6, e = i & 63;
        xs[r * 65 + e] = xin[(R0 + r) * 64 + e];
    }
    for (int i = tid; i < 16384; i += 512) {
        int e = i >> 8, f = i & 255;
        Wb[i] = Wff1[f * 64 + e];    // W1T[e][f]
    }
    __syncthreads();
    int l = tid & 63, g = tid >> 6;
    {
        float acc[4][8];
        #pragma unroll
        for (int j = 0; j < 4; ++j)
            #pragma unroll
            for (int ri = 0; ri < 8; ++ri) acc[j][ri] = 0.f;
        for (int e = 0; e < 64; ++e) {
            float xr[8];
            #pragma unroll
            for (int ri = 0; ri < 8; ++ri) xr[ri] = xs[(g * 8 + ri) * 65 + e];
            #pragma unroll
            for (int j = 0; j < 4; ++j) {
                float wv = Wb[e * 256 + l + 64 * j];
                #pragma unroll
                for (int ri = 0; ri < 8; ++ri) acc[j][ri] += xr[ri] * wv;
            }
        }
        #pragma unroll
        for (int j = 0; j < 4; ++j) {
            float bb = bff1[l + 64 * j];
            #pragma unroll
            for (int ri = 0; ri < 8; ++ri)
                fhT[(l + 64 * j) * 65 + g * 8 + ri] = fmaxf(acc[j][ri] + bb, 0.f);
        }
    }
    __syncthreads();
    for (int i = tid; i < 16384; i += 512) {
        int f = i >> 6, o = i & 63;
        Wb[i] = Wff2[o * 256 + f];   // W2T[f][o]
    }
    __syncthreads();
    float acc2[8];
    #pragma unroll
    for (int oi = 0; oi < 8; ++oi) acc2[oi] = 0.f;
    for (int f = 0; f < 256; ++f) {
        float fv = fhT[f * 65 + l];
        float4 wa = *(const float4*)(Wb + f * 64 + g * 8);
        float4 wb_ = *(const float4*)(Wb + f * 64 + g * 8 + 4);
        acc2[0] += fv * wa.x;  acc2[1] += fv * wa.y;
        acc2[2] += fv * wa.z;  acc2[3] += fv * wa.w;
        acc2[4] += fv * wb_.x; acc2[5] += fv * wb_.y;
        acc2[6] += fv * wb_.z; acc2[7] += fv * wb_.w;
    }
    __syncthreads();                 // all reads of Wb/fhT done
    float* lnb = Wb;                 // 64*65
    float* mM = Wb + 4160;
    float* mI = Wb + 4224;
    #pragma unroll
    for (int oi = 0; oi < 8; ++oi) {
        int o = g * 8 + oi;
        lnb[l * 65 + o] = acc2[oi] + bff2[o] + xs[l * 65 + o];
    }
    __syncthreads();
    int r = tid >> 3, sb = tid & 7;
    float v[8];
    float sm = 0.f;
    #pragma unroll
    for (int i = 0; i < 8; ++i) { v[i] = lnb[r * 65 + sb + 8 * i]; sm += v[i]; }
    sm += __shfl_xor(sm, 1); sm += __shfl_xor(sm, 2); sm += __shfl_xor(sm, 4);
    float mean = sm * (1.f / 64.f);
    float vs = 0.f;
    #pragma unroll
    for (int i = 0; i < 8; ++i) { float dv = v[i] - mean; vs += dv * dv; }
    vs += __shfl_xor(vs, 1); vs += __shfl_xor(vs, 2); vs += __shfl_xor(vs, 4);
    float inv = rsqrtf(vs * (1.f / 64.f) + 1e-5f);
    if (sb == 0) { mM[r] = mean; mI[r] = inv; }
    __syncthreads();
    for (int i = tid; i < 4096; i += 512) {
        int rr = i >> 6, o = i & 63;
        US[(R0 + rr) * 64 + o] = (lnb[rr * 65 + o] - mM[rr]) * mI[rr] * w2[o] + b2[o];
    }
}

// ---------------------------------------------------------------------------
// A3: gate + blend + final 1x1 conv E->C with transpose to (B,C,N,T)
// ---------------------------------------------------------------------------
__global__ void __launch_bounds__(256) k_A3(
    const float* __restrict__ US, const float* __restrict__ Xc,
    const float* __restrict__ Wfs, const float* __restrict__ bfs,
    const float* __restrict__ Wfg, const float* __restrict__ bfg,
    const float* __restrict__ Wc11, const float* __restrict__ bc11,
    float* __restrict__ out)
{
    __shared__ float us[1024], xc[1024], WsT[4096], WgT[4096], WcT[2048], op[16 * 65];
    size_t R0 = (size_t)blockIdx.x * 16;
    for (int l = threadIdx.x; l < 4096; l += 256) {
        int e = l >> 6, o = l & 63;
        WsT[l] = Wfs[o * 64 + e];
        WgT[l] = Wfg[o * 64 + e];
    }
    for (int l = threadIdx.x; l < 2048; l += 256) {
        int e = l >> 5, oc = l & 31;
        WcT[l] = Wc11[oc * 64 + e];
    }
    for (int l = threadIdx.x; l < 1024; l += 256) {
        us[l] = US[R0 * 64 + l];
        xc[l] = Xc[R0 * 64 + l];
    }
    __syncthreads();
    int o = threadIdx.x & 63, w = threadIdx.x >> 6;
    for (int k = 0; k < 4; ++k) {
        int r = w + (k << 2);
        float a1 = bfs[o], a2 = bfg[o];
        for (int e = 0; e < 64; ++e) {
            a1 += us[r * 64 + e] * WsT[e * 64 + o];
            a2 += xc[r * 64 + e] * WgT[e * 64 + o];
        }
        float g = 1.f / (1.f + expf(-(a1 + a2)));
        op[r * 65 + o] = g * us[r * 64 + o] + (1.f - g) * xc[r * 64 + o];
    }
    __syncthreads();
    int b = (int)(R0 / 4800);
    int rr = (int)(R0 % 4800);
    for (int k2 = 0; k2 < 2; ++k2) {
        int idx = threadIdx.x + (k2 << 8);
        int rloc = idx & 15, oc = idx >> 4;
        float acc = bc11[oc];
        for (int e = 0; e < 64; ++e) acc += op[rloc * 65 + e] * WcT[e * 32 + oc];
        out[(size_t)(b * 32 + oc) * 4800 + rr + rloc] = acc;
    }
}

// ---------------------------------------------------------------------------
extern "C" void kernel_launch(void* const* d_in, const int* in_sizes, int n_in,
                              void* d_out, int out_size, void* d_ws, size_t ws_size,
                              hipStream_t stream)
{
    (void)in_sizes; (void)n_in; (void)out_size; (void)ws_size;
    const float* query = (const float*)d_in[2];
    const float* s0    = (const float*)d_in[3];
    const float* s1    = (const float*)d_in[4];
    const float* sr0   = (const float*)d_in[5];
    const float* sr1   = (const float*)d_in[6];
    const float* Mrg   = (const float*)d_in[7];
    const float* Mor   = (const float*)d_in[8];
    const float* D_S   = (const float*)d_in[9];
    const float* Wc1   = (const float*)d_in[10];
    const float* bc1   = (const float*)d_in[11];
    const float* Wc11  = (const float*)d_in[12];
    const float* bc11  = (const float*)d_in[13];
    const float* Wg    = (const float*)d_in[14];
    const float* bg    = (const float*)d_in[15];
    const float* Wem   = (const float*)d_in[16];
    const float* bem   = (const float*)d_in[17];
    const float* Wq    = (const float*)d_in[18];
    const float* Wk    = (const float*)d_in[19];
    const float* Wv    = (const float*)d_in[20];
    const float* Wfc   = (const float*)d_in[21];
    const float* bfc   = (const float*)d_in[22];
    const float* ln1w  = (const float*)d_in[23];
    const float* ln1b  = (const float*)d_in[24];
    const float* ln2w  = (const float*)d_in[25];
    const float* ln2b  = (const float*)d_in[26];
    const float* Wff1  = (const float*)d_in[27];
    const float* bff1  = (const float*)d_in[28];
    const float* Wff2  = (const float*)d_in[29];
    const float* bff2  = (const float*)d_in[30];
    const float* Wfs   = (const float*)d_in[31];
    const float* bfs   = (const float*)d_in[32];
    const float* Wfg   = (const float*)d_in[33];
    const float* bfg   = (const float*)d_in[34];

    float* ws = (float*)d_ws;
    size_t off = 0;
    auto alloc = [&](size_t n) { float* p = ws + off; off += n; return p; };
    float* q_buf = alloc(4915200);   // (B,N,T,E)
    float* Xc    = alloc(4915200);   // (B,N,T,E) -- doubles as qq pre-CHGCN
    float* x_buf = alloc(4915200);   // doubles as attnO (in-place A1)
    float* US    = alloc(4915200);   // doubles as vv pre-A2
    float* ho    = alloc(2457600);   // (B,C,N,T)
    float* t0    = alloc(2457600);
    float* t1    = alloc(2457600);   // t0+t1 contiguous: doubles as kk
    float* xr    = alloc(393216);    // (B,C,R,T)
    float* tr0   = alloc(393216);
    float* tr1   = alloc(393216);
    float* hr    = alloc(393216);
    float* xsg   = alloc(98304);     // (B,C,G,T)
    float* tg0   = alloc(98304);
    float* tg1   = alloc(98304);
    float* xg0   = alloc(98304);
    float* dsb   = alloc(25600);     // (N,E)
    float* Ag    = alloc(256);
    float* sg0   = alloc(256);
    float* sg1   = alloc(256);

    float* qq    = Xc;               // live only during [k_qkv, k_attn2]
    float* kk    = t0;               // (contiguous with t1)
    float* vv    = US;
    float* attnO = x_buf;

    float* out_main = (float*)d_out;          // (B,C,N,T)
    float* out_xc   = out_main + 2457600;     // (B,C,R,T) final hr
    float* out_xs   = out_main + 2850816;     // (B,C,G,T) final xg

    hipFuncSetAttribute((const void*)k_attn2,
                        hipFuncAttributeMaxDynamicSharedMemorySize, 159872);
    hipFuncSetAttribute((const void*)k_A2n,
                        hipFuncAttributeMaxDynamicSharedMemorySize, 148736);

    hipMemsetAsync(Ag, 0, 256 * sizeof(float), stream);

    // ---- Transformer front (before CHGCN so qq/kk/vv can alias Xc/t0t1/US)
    k_ds<<<400, 64, 0, stream>>>(D_S, Wem, bem, dsb);
    k_conv1<<<800, 256, 0, stream>>>(query, Wc1, bc1, dsb, q_buf);
    k_qkv<<<dim3(384, 7), 256, 0, stream>>>(q_buf, Wq, Wk, Wv, qq, kk, vv);
    k_attn2<<<768, 512, 159872, stream>>>(qq, kk, vv, attnO);
    k_A1<<<2400, 256, 0, stream>>>(attnO, Wfc, bfc, q_buf, ln1w, ln1b, x_buf);
    k_A2n<<<1200, 512, 148736, stream>>>(x_buf, Wff1, bff1, Wff2, bff2,
                                         ln2w, ln2b, US);

    // ---- CHGCN ----
    k_spatial<<<dim3(512, 4), 256, 0, stream>>>(s0, 1, 400, 400, query, nullptr, 1.f, 0, t0);
    k_spatial<<<dim3(512, 4), 256, 0, stream>>>(s1, 1, 400, 400, query, nullptr, 1.f, 0, t1);
    k_gcn_combine<<<800, 256, 0, stream>>>(query, t0, t1, Wg, bg, 400, ho);
    k_spatial<<<dim3(512, 1), 256, 0, stream>>>(Mor, 1, 400, 64, query, nullptr, 1.f, 0, xr);
    k_spatial<<<dim3(512, 1), 256, 0, stream>>>(sr0, 1, 64, 64, xr, nullptr, 1.f, 0, tr0);
    k_spatial<<<dim3(512, 1), 256, 0, stream>>>(sr1, 1, 64, 64, xr, nullptr, 1.f, 0, tr1);
    k_gcn_combine<<<128, 256, 0, stream>>>(xr, tr0, tr1, Wg, bg, 64, hr);
    k_spatial<<<dim3(512, 1), 256, 0, stream>>>(Mrg, 1, 64, 16, xr, nullptr, 1.f, 0, xsg);
    k_agp<<<24, 256, 0, stream>>>(xsg, Ag);
    k_agf<<<1, 64, 0, stream>>>(Ag, sg0, sg1);
    k_spatial<<<dim3(512, 1), 256, 0, stream>>>(sg0, 1, 16, 16, xsg, nullptr, 1.f, 0, tg0);
    k_spatial<<<dim3(512, 1), 256, 0, stream>>>(sg1, 1, 16, 16, xsg, nullptr, 1.f, 0, tg1);
    k_gcn_combine<<<32, 256, 0, stream>>>(xsg, tg0, tg1, Wg, bg, 16, xg0);
    k_spatial<<<dim3(512, 1), 256, 0, stream>>>(Mrg, 0, 16, 64, xg0, hr, 0.5f, 1, hr);
    k_spatial<<<dim3(512, 4), 256, 0, stream>>>(Mor, 0, 64, 400, hr, ho, 0.5f, 1, ho);
    k_spatial<<<dim3(512, 1), 256, 0, stream>>>(Mor, 1, 400, 64, ho, hr, 0.5f, 1, out_xc);
    k_spatial<<<dim3(512, 1), 256, 0, stream>>>(Mrg, 1, 64, 16, out_xc, xg0, 0.5f, 1, out_xs);

    // ---- Tail ----
    k_conv1<<<800, 256, 0, stream>>>(ho, Wc1, bc1, nullptr, Xc);
    k_A3<<<4800, 256, 0, stream>>>(US, Xc, Wfs, bfs, Wfg, bfg, Wc11, bc11, out_main);
}

// Round 4
// 2002.457 us; speedup vs baseline: 1.7612x; 1.0315x over previous
//
#include <hip/hip_runtime.h>

// Dims: B=16 C=32 N=400 T=12 R=64 G=16 E=64 H=2 DH=32 FE=256
#define TT 12

// ---------------------------------------------------------------------------
// Generic spatial contraction over (b,c) batches, vo-chunked via blockIdx.y:
// out[bc, vo, t] = base? base + scale*relu?(acc) : acc
// acc = sum_vi M * in[bc, vi, t]; orientT: M[vi*Vout+vo], else M[vo*Vin+vi]
// ---------------------------------------------------------------------------
__global__ void __launch_bounds__(256) k_spatial(
    const float* __restrict__ M, int orientT, int Vin, int Vout,
    const float* __restrict__ in, const float* __restrict__ base,
    float scale, int do_relu, float* __restrict__ out)
{
    __shared__ float in_lds[400 * TT];
    int bc = blockIdx.x;
    const float* ib = in + (size_t)bc * Vin * TT;
    for (int i = threadIdx.x; i < Vin * TT; i += 256) in_lds[i] = ib[i];
    __syncthreads();
    int chunk = Vout / gridDim.y;
    int vo0 = blockIdx.y * chunk;
    size_t obase = (size_t)bc * Vout * TT;
    for (int idx = threadIdx.x; idx < chunk * TT; idx += 256) {
        int vo = vo0 + idx / TT, t = idx - (idx / TT) * TT;
        float acc = 0.f;
        if (orientT) {
            for (int vi = 0; vi < Vin; ++vi)
                acc += M[(size_t)vi * Vout + vo] * in_lds[vi * TT + t];
        } else {
            const float* Mr = M + (size_t)vo * Vin;
            for (int vi = 0; vi < Vin; ++vi)
                acc += Mr[vi] * in_lds[vi * TT + t];
        }
        if (do_relu) acc = fmaxf(acc, 0.f);
        acc *= scale;
        size_t oi = obase + (size_t)vo * TT + t;
        if (base) acc += base[oi];
        out[oi] = acc;
    }
}

// ---------------------------------------------------------------------------
// GCN combine: out[b,o,v,t] = bias[o] + sum_c W[o,c]*x + W[o,32+c]*t0 + W[o,64+c]*t1
// ---------------------------------------------------------------------------
__global__ void __launch_bounds__(256) k_gcn_combine(
    const float* __restrict__ x, const float* __restrict__ t0in,
    const float* __restrict__ t1in, const float* __restrict__ W,
    const float* __restrict__ bias, int V, float* __restrict__ out)
{
    __shared__ float xs_[96 * 33], t0s[96 * 33], t1s[96 * 33], WT[96 * 32];
    int nb = V / 8;
    int b = blockIdx.x / nb, n0 = (blockIdx.x % nb) * 8;
    for (int l = threadIdx.x; l < 96 * 32; l += 256) {
        int c3 = l >> 5, o = l & 31;
        WT[l] = W[o * 96 + c3];
    }
    for (int l = threadIdx.x; l < 3072; l += 256) {
        int c = l / 96, s = l - c * 96;
        size_t g = ((size_t)((b * 32 + c) * V) + n0 + s / 12) * 12 + (s % 12);
        xs_[s * 33 + c] = x[g];
        t0s[s * 33 + c] = t0in[g];
        t1s[s * 33 + c] = t1in[g];
    }
    __syncthreads();
    for (int idx = threadIdx.x; idx < 3072; idx += 256) {
        int o = idx / 96, s = idx - o * 96;
        float acc = bias[o];
        for (int c = 0; c < 32; ++c) {
            float a = xs_[s * 33 + c] * WT[c * 32 + o];
            float b2 = t0s[s * 33 + c] * WT[(32 + c) * 32 + o];
            float c2 = t1s[s * 33 + c] * WT[(64 + c) * 32 + o];
            acc += a + b2 + c2;
        }
        out[((size_t)(b * 32 + o) * V + n0) * 12 + s] = acc;
    }
}

// ---------------------------------------------------------------------------
// 1x1 conv C->E with layout change (B,C,N,T) -> (B,N,T,E), optional +ds[n,e]
// ---------------------------------------------------------------------------
__global__ void __launch_bounds__(256) k_conv1(
    const float* __restrict__ x, const float* __restrict__ W,
    const float* __restrict__ bias, const float* __restrict__ dsadd,
    float* __restrict__ out)
{
    __shared__ float xs_[96 * 33];
    __shared__ float WT[2048];
    int b = blockIdx.x / 50, n0 = (blockIdx.x % 50) * 8;
    for (int l = threadIdx.x; l < 2048; l += 256) {
        int c = l >> 6, o = l & 63;
        WT[l] = W[o * 32 + c];
    }
    for (int l = threadIdx.x; l < 3072; l += 256) {
        int c = l / 96, s = l - c * 96;
        xs_[s * 33 + c] = x[((size_t)(b * 32 + c) * 400 + n0 + s / 12) * 12 + (s % 12)];
    }
    __syncthreads();
    for (int idx = threadIdx.x; idx < 6144; idx += 256) {
        int s = idx >> 6, o = idx & 63;
        float acc = bias[o];
        for (int c = 0; c < 32; ++c) acc += xs_[s * 33 + c] * WT[(c << 6) + o];
        if (dsadd) acc += dsadd[(n0 + s / 12) * 64 + o];
        out[((size_t)b * 4800 + n0 * 12 + s) * 64 + o] = acc;
    }
}

// ---------------------------------------------------------------------------
// ds[n,e] = sum_m D_S[n,m] * W_embed[e,m] + b_embed[e]
// ---------------------------------------------------------------------------
__global__ void __launch_bounds__(64) k_ds(
    const float* __restrict__ D_S, const float* __restrict__ Wem,
    const float* __restrict__ bem, float* __restrict__ ds)
{
    __shared__ float row[400];
    int n = blockIdx.x;
    for (int i = threadIdx.x; i < 400; i += 64) row[i] = D_S[n * 400 + i];
    __syncthreads();
    int e = threadIdx.x;
    float acc = bem[e];
    const float* we = Wem + (size_t)e * 400;
    for (int m = 0; m < 400; ++m) acc += row[m] * we[m];
    ds[n * 64 + e] = acc;
}

// ---------------------------------------------------------------------------
// Ag partial (reference's mismatched reshape contraction)
// ---------------------------------------------------------------------------
__global__ void __launch_bounds__(256) k_agp(const float* __restrict__ xs,
                                             float* __restrict__ Ag)
{
    __shared__ float A[256 * 17], Bv[256 * 17];
    int i = blockIdx.x * 256 + threadIdx.x;  // < 6144
    int c1 = i / 192, b1 = (i / 12) & 15, t1 = i % 12;
    int t2 = i >> 9, b2 = (i >> 5) & 15, c2 = i & 31;
    for (int g = 0; g < 16; ++g) {
        A[threadIdx.x * 17 + g] = xs[((size_t)(b1 * 32 + c1) * 16 + g) * 12 + t1];
        Bv[threadIdx.x * 17 + g] = xs[((size_t)(b2 * 32 + c2) * 16 + g) * 12 + t2];
    }
    __syncthreads();
    int g1 = threadIdx.x >> 4, g2 = threadIdx.x & 15;
    float acc = 0.f;
    for (int k = 0; k < 256; ++k) acc += A[k * 17 + g1] * Bv[k * 17 + g2];
    atomicAdd(&Ag[threadIdx.x], acc);
}

// ---------------------------------------------------------------------------
// Ag -> relu(Ag-0.5) -> sg0/sg1 softmax(asym_adj)
// ---------------------------------------------------------------------------
__global__ void __launch_bounds__(64) k_agf(const float* __restrict__ Ag,
                                            float* __restrict__ sg0,
                                            float* __restrict__ sg1)
{
    __shared__ float Ar[256], rs[16], cs[16];
    int tid = threadIdx.x;
    for (int l = tid; l < 256; l += 64) Ar[l] = fmaxf(Ag[l] - 0.5f, 0.f);
    __syncthreads();
    if (tid < 16) {
        float r = 0.f, c = 0.f;
        for (int j = 0; j < 16; ++j) { r += Ar[tid * 16 + j]; c += Ar[j * 16 + tid]; }
        rs[tid] = (r > 0.f) ? 1.f / r : 0.f;
        cs[tid] = (c > 0.f) ? 1.f / c : 0.f;
    }
    __syncthreads();
    if (tid < 16) {
        float v[16], m, s;
        m = -1e30f;
        for (int j = 0; j < 16; ++j) { v[j] = Ar[tid * 16 + j] * rs[tid]; m = fmaxf(m, v[j]); }
        s = 0.f;
        for (int j = 0; j < 16; ++j) { v[j] = expf(v[j] - m); s += v[j]; }
        for (int j = 0; j < 16; ++j) sg0[tid * 16 + j] = v[j] / s;
        m = -1e30f;
        for (int j = 0; j < 16; ++j) { v[j] = Ar[j * 16 + tid] * cs[tid]; m = fmaxf(m, v[j]); }
        s = 0.f;
        for (int j = 0; j < 16; ++j) { v[j] = expf(v[j] - m); s += v[j]; }
        for (int j = 0; j < 16; ++j) sg1[tid * 16 + j] = v[j] / s;
    }
}

// ---------------------------------------------------------------------------
// QKV projection: qq/kk/vv[g][n][d] = sum_dd q[b,n,t,h*32+dd]*W{q,k,v}[d][dd]
// g = b*24 + t*2 + h. Grid (384, 7), block 256 (64-row tiles).
// ---------------------------------------------------------------------------
__global__ void __launch_bounds__(256) k_qkv(
    const float* __restrict__ q, const float* __restrict__ Wq,
    const float* __restrict__ Wk, const float* __restrict__ Wv,
    float* __restrict__ qq, float* __restrict__ kk, float* __restrict__ vv)
{
    __shared__ float qs[64 * 33], wqT[1024], wkT[1024], wvT[1024];
    int g = blockIdx.x, n0 = blockIdx.y * 64;
    int b = g / 24, rem = g % 24, t = rem >> 1, h = rem & 1;
    int tid = threadIdx.x;
    for (int i = tid; i < 1024; i += 256) {
        int dd = i >> 5, e = i & 31;
        wqT[i] = Wq[e * 32 + dd];
        wkT[i] = Wk[e * 32 + dd];
        wvT[i] = Wv[e * 32 + dd];
    }
    for (int i = tid; i < 2048; i += 256) {
        int n = i >> 5, dd = i & 31;
        int gn = n0 + n;
        qs[n * 33 + dd] = (gn < 400)
            ? q[((size_t)b * 4800 + gn * 12 + t) * 64 + h * 32 + dd] : 0.f;
    }
    __syncthreads();
    int e = tid & 31, ng = tid >> 5;
    float aq[8], ak[8], av[8];
    #pragma unroll
    for (int k = 0; k < 8; ++k) { aq[k] = 0.f; ak[k] = 0.f; av[k] = 0.f; }
    for (int dd = 0; dd < 32; ++dd) {
        float wq = wqT[dd * 32 + e], wk = wkT[dd * 32 + e], wv = wvT[dd * 32 + e];
        #pragma unroll
        for (int k = 0; k < 8; ++k) {
            float xv = qs[(ng + 8 * k) * 33 + dd];
            aq[k] += xv * wq; ak[k] += xv * wk; av[k] += xv * wv;
        }
    }
    #pragma unroll
    for (int k = 0; k < 8; ++k) {
        int gn = n0 + ng + 8 * k;
        if (gn < 400) {
            size_t a = ((size_t)g * 400 + gn) * 32 + e;
            qq[a] = aq[k]; kk[a] = ak[k]; vv[a] = av[k];
        }
    }
}

// ---------------------------------------------------------------------------
// Attention over nodes. Grid 768 = (b,t,h)x2 row-halves; 512 thr = 8 waves.
// Barrier-free row loop: each wave register-tiles 4 q-rows.
// Dyn LDS: kkT 32x449 (zero-padded keys 400..447) + vv 400x32 + pbuf 8x1600
// = 39968 floats = 159872 B.
// __launch_bounds__(512, 2): LDS already caps at 1 block/CU = 2 waves/EU;
// without the ",2" the allocator capped VGPRs at 128 and spilled ~1.7 GB of
// scratch traffic to HBM (round-2 profile: 832 MB FETCH + 927 MB WRITE).
// ---------------------------------------------------------------------------
__global__ void __launch_bounds__(512, 2) k_attn2(
    const float* __restrict__ qq, const float* __restrict__ kk,
    const float* __restrict__ vv, float* __restrict__ attnO)
{
    extern __shared__ float lds[];
    float* kkT = lds;             // 32*449
    float* vvs = kkT + 14368;     // 400*32
    float* pbuf = vvs + 12800;    // 8 waves * 4*400

    int g = blockIdx.x >> 1, rh = blockIdx.x & 1;
    const float* qq_g = qq + (size_t)g * 12800;
    const float* kk_g = kk + (size_t)g * 12800;
    const float* vv_g = vv + (size_t)g * 12800;
    int tid = threadIdx.x;

    for (int i = tid; i < 1568; i += 512) {          // zero pad cols 400..448
        int d = i / 49, c = i - d * 49;
        kkT[d * 449 + 400 + c] = 0.f;
    }
    for (int i = tid; i < 12800; i += 512) {
        int k = i >> 5, d = i & 31;
        kkT[d * 449 + k] = kk_g[i];
        vvs[i] = vv_g[i];
    }
    __syncthreads();

    int w = tid >> 6, l = tid & 63;
    float* pw = pbuf + w * 1600;
    int b = g / 24, rem = g % 24, t = rem >> 1, h = rem & 1;
    size_t obase = ((size_t)b * 4800 + t) * 64 + h * 32;

    for (int r0 = rh * 200 + w * 4; r0 < rh * 200 + 200; r0 += 32) {
        float e[4][7];
        #pragma unroll
        for (int ri = 0; ri < 4; ++ri)
            #pragma unroll
            for (int j = 0; j < 7; ++j) e[ri][j] = 0.f;

        for (int db = 0; db < 4; ++db) {
            float qreg[4][8];
            #pragma unroll
            for (int ri = 0; ri < 4; ++ri)
                #pragma unroll
                for (int dd = 0; dd < 8; ++dd)
                    qreg[ri][dd] = qq_g[(r0 + ri) * 32 + db * 8 + dd];
            #pragma unroll
            for (int j = 0; j < 7; ++j) {
                #pragma unroll
                for (int dd = 0; dd < 8; ++dd) {
                    float kv = kkT[(db * 8 + dd) * 449 + j * 64 + l];
                    e[0][j] += qreg[0][dd] * kv;
                    e[1][j] += qreg[1][dd] * kv;
                    e[2][j] += qreg[2][dd] * kv;
                    e[3][j] += qreg[3][dd] * kv;
                }
            }
        }
        bool ok6 = (l < 16);
        float s[4];
        #pragma unroll
        for (int ri = 0; ri < 4; ++ri) {
            if (!ok6) e[ri][6] = -1e30f;
            float m = e[ri][0];
            #pragma unroll
            for (int j = 1; j < 7; ++j) m = fmaxf(m, e[ri][j]);
            #pragma unroll
            for (int off = 32; off; off >>= 1) m = fmaxf(m, __shfl_xor(m, off));
            float ss = 0.f;
            #pragma unroll
            for (int j = 0; j < 7; ++j) {
                e[ri][j] = __expf((e[ri][j] - m) * 0.125f);
                ss += e[ri][j];
            }
            #pragma unroll
            for (int off = 32; off; off >>= 1) ss += __shfl_xor(ss, off);
            s[ri] = ss;
            #pragma unroll
            for (int j = 0; j < 6; ++j) pw[ri * 400 + j * 64 + l] = e[ri][j];
            if (ok6) pw[ri * 400 + 384 + l] = e[ri][6];
        }
        asm volatile("" ::: "memory");   // wave-private LDS: in-order DS pipe

        int hh = l >> 5, d = l & 31;
        float o0 = 0.f, o1 = 0.f, o2 = 0.f, o3 = 0.f;
        int kb0 = hh * 200;
        for (int kb = 0; kb < 200; kb += 4) {
            int k = kb0 + kb;
            float4 p0 = *(const float4*)(pw + 0 * 400 + k);
            float4 p1 = *(const float4*)(pw + 1 * 400 + k);
            float4 p2 = *(const float4*)(pw + 2 * 400 + k);
            float4 p3 = *(const float4*)(pw + 3 * 400 + k);
            float v0 = vvs[(k + 0) * 32 + d];
            float v1 = vvs[(k + 1) * 32 + d];
            float v2 = vvs[(k + 2) * 32 + d];
            float v3 = vvs[(k + 3) * 32 + d];
            o0 += p0.x * v0 + p0.y * v1 + p0.z * v2 + p0.w * v3;
            o1 += p1.x * v0 + p1.y * v1 + p1.z * v2 + p1.w * v3;
            o2 += p2.x * v0 + p2.y * v1 + p2.z * v2 + p2.w * v3;
            o3 += p3.x * v0 + p3.y * v1 + p3.z * v2 + p3.w * v3;
        }
        asm volatile("" ::: "memory");
        o0 += __shfl_down(o0, 32);
        o1 += __shfl_down(o1, 32);
        o2 += __shfl_down(o2, 32);
        o3 += __shfl_down(o3, 32);
        if (l < 32) {
            attnO[obase + (size_t)(r0 + 0) * 768 + d] = o0 / s[0];
            attnO[obase + (size_t)(r0 + 1) * 768 + d] = o1 / s[1];
            attnO[obase + (size_t)(r0 + 2) * 768 + d] = o2 / s[2];
            attnO[obase + (size_t)(r0 + 3) * 768 + d] = o3 / s[3];
        }
    }
}

// ---------------------------------------------------------------------------
// A1: x = LN(attnO @ Wfc^T + bfc + q); 32 rows/block (in-place safe per block)
// ---------------------------------------------------------------------------
__global__ void __launch_bounds__(256) k_A1(
    const float* __restrict__ attnO, const float* __restrict__ Wfc,
    const float* __restrict__ bfc, const float* __restrict__ qbuf,
    const float* __restrict__ w1, const float* __restrict__ b1,
    float* __restrict__ xout)
{
    __shared__ float WT[4096], ao[2048], qs[2048];
    size_t r0 = (size_t)blockIdx.x * 32;
    for (int l = threadIdx.x; l < 4096; l += 256) {
        int e = l >> 6, o = l & 63;
        WT[l] = Wfc[o * 64 + e];
    }
    for (int l = threadIdx.x; l < 2048; l += 256) {
        ao[l] = attnO[r0 * 64 + l];
        qs[l] = qbuf[r0 * 64 + l];
    }
    __syncthreads();
    int o = threadIdx.x & 63, w = threadIdx.x >> 6;
    for (int k = 0; k < 8; ++k) {
        int r = w + (k << 2);
        float acc = bfc[o];
        for (int e = 0; e < 64; ++e) acc += ao[r * 64 + e] * WT[e * 64 + o];
        float val = acc + qs[r * 64 + o];
        float sum = val;
        for (int off = 32; off; off >>= 1) sum += __shfl_xor(sum, off);
        float mean = sum * (1.f / 64.f);
        float dv = val - mean;
        float vs = dv * dv;
        for (int off = 32; off; off >>= 1) vs += __shfl_xor(vs, off);
        float inv = rsqrtf(vs * (1.f / 64.f) + 1e-5f);
        xout[(r0 + r) * 64 + o] = dv * inv * w1[o] + b1[o];
    }
}

// ---------------------------------------------------------------------------
// A2 fused FF: US = LN(relu(x@W1^T+b1)@W2^T+b2 + x). 64 rows/block, 512 thr.
// Dyn LDS: xs 64x65 + Wbuf 16384 + fhT 256x65 = 37184 floats = 148736 B
// __launch_bounds__(512, 2): same spill-guard rationale as k_attn2.
// ---------------------------------------------------------------------------
__global__ void __launch_bounds__(512, 2) k_A2n(
    const float* __restrict__ xin, const float* __restrict__ Wff1,
    const float* __restrict__ bff1, const float* __restrict__ Wff2,
    const float* __restrict__ bff2, const float* __restrict__ w2,
    const float* __restrict__ b2, float* __restrict__ US)
{
    extern __shared__ float lds[];
    float* xs = lds;             // 64*65 = 4160
    float* Wb = xs + 4160;       // 16384
    float* fhT = Wb + 16384;     // 256*65 = 16640
    size_t R0 = (size_t)blockIdx.x * 64;
    int tid = threadIdx.x;
    for (int i = tid; i < 4096; i += 512) {
        int r = i >> 6, e = i & 63;
        xs[r * 65 + e] = xin[(R0 + r) * 64 + e];
    }
    for (int i = tid; i < 16384; i += 512) {
        int e = i >> 8, f = i & 255;
        Wb[i] = Wff1[f * 64 + e];    // W1T[e][f]
    }
    __syncthreads();
    int l = tid & 63, g = tid >> 6;
    {
        float acc[4][8];
        #pragma unroll
        for (int j = 0; j < 4; ++j)
            #pragma unroll
            for (int ri = 0; ri < 8; ++ri) acc[j][ri] = 0.f;
        for (int e = 0; e < 64; ++e) {
            float xr[8];
            #pragma unroll
            for (int ri = 0; ri < 8; ++ri) xr[ri] = xs[(g * 8 + ri) * 65 + e];
            #pragma unroll
            for (int j = 0; j < 4; ++j) {
                float wv = Wb[e * 256 + l + 64 * j];
                #pragma unroll
                for (int ri = 0; ri < 8; ++ri) acc[j][ri] += xr[ri] * wv;
            }
        }
        #pragma unroll
        for (int j = 0; j < 4; ++j) {
            float bb = bff1[l + 64 * j];
            #pragma unroll
            for (int ri = 0; ri < 8; ++ri)
                fhT[(l + 64 * j) * 65 + g * 8 + ri] = fmaxf(acc[j][ri] + bb, 0.f);
        }
    }
    __syncthreads();
    for (int i = tid; i < 16384; i += 512) {
        int f = i >> 6, o = i & 63;
        Wb[i] = Wff2[o * 256 + f];   // W2T[f][o]
    }
    __syncthreads();
    float acc2[8];
    #pragma unroll
    for (int oi = 0; oi < 8; ++oi) acc2[oi] = 0.f;
    for (int f = 0; f < 256; ++f) {
        float fv = fhT[f * 65 + l];
        float4 wa = *(const float4*)(Wb + f * 64 + g * 8);
        float4 wb_ = *(const float4*)(Wb + f * 64 + g * 8 + 4);
        acc2[0] += fv * wa.x;  acc2[1] += fv * wa.y;
        acc2[2] += fv * wa.z;  acc2[3] += fv * wa.w;
        acc2[4] += fv * wb_.x; acc2[5] += fv * wb_.y;
        acc2[6] += fv * wb_.z; acc2[7] += fv * wb_.w;
    }
    __syncthreads();                 // all reads of Wb/fhT done
    float* lnb = Wb;                 // 64*65
    float* mM = Wb + 4160;
    float* mI = Wb + 4224;
    #pragma unroll
    for (int oi = 0; oi < 8; ++oi) {
        int o = g * 8 + oi;
        lnb[l * 65 + o] = acc2[oi] + bff2[o] + xs[l * 65 + o];
    }
    __syncthreads();
    int r = tid >> 3, sb = tid & 7;
    float v[8];
    float sm = 0.f;
    #pragma unroll
    for (int i = 0; i < 8; ++i) { v[i] = lnb[r * 65 + sb + 8 * i]; sm += v[i]; }
    sm += __shfl_xor(sm, 1); sm += __shfl_xor(sm, 2); sm += __shfl_xor(sm, 4);
    float mean = sm * (1.f / 64.f);
    float vs = 0.f;
    #pragma unroll
    for (int i = 0; i < 8; ++i) { float dv = v[i] - mean; vs += dv * dv; }
    vs += __shfl_xor(vs, 1); vs += __shfl_xor(vs, 2); vs += __shfl_xor(vs, 4);
    float inv = rsqrtf(vs * (1.f / 64.f) + 1e-5f);
    if (sb == 0) { mM[r] = mean; mI[r] = inv; }
    __syncthreads();
    for (int i = tid; i < 4096; i += 512) {
        int rr = i >> 6, o = i & 63;
        US[(R0 + rr) * 64 + o] = (lnb[rr * 65 + o] - mM[rr]) * mI[rr] * w2[o] + b2[o];
    }
}

// ---------------------------------------------------------------------------
// A3: gate + blend + final 1x1 conv E->C with transpose to (B,C,N,T)
// ---------------------------------------------------------------------------
__global__ void __launch_bounds__(256) k_A3(
    const float* __restrict__ US, const float* __restrict__ Xc,
    const float* __restrict__ Wfs, const float* __restrict__ bfs,
    const float* __restrict__ Wfg, const float* __restrict__ bfg,
    const float* __restrict__ Wc11, const float* __restrict__ bc11,
    float* __restrict__ out)
{
    __shared__ float us[1024], xc[1024], WsT[4096], WgT[4096], WcT[2048], op[16 * 65];
    size_t R0 = (size_t)blockIdx.x * 16;
    for (int l = threadIdx.x; l < 4096; l += 256) {
        int e = l >> 6, o = l & 63;
        WsT[l] = Wfs[o * 64 + e];
        WgT[l] = Wfg[o * 64 + e];
    }
    for (int l = threadIdx.x; l < 2048; l += 256) {
        int e = l >> 5, oc = l & 31;
        WcT[l] = Wc11[oc * 64 + e];
    }
    for (int l = threadIdx.x; l < 1024; l += 256) {
        us[l] = US[R0 * 64 + l];
        xc[l] = Xc[R0 * 64 + l];
    }
    __syncthreads();
    int o = threadIdx.x & 63, w = threadIdx.x >> 6;
    for (int k = 0; k < 4; ++k) {
        int r = w + (k << 2);
        float a1 = bfs[o], a2 = bfg[o];
        for (int e = 0; e < 64; ++e) {
            a1 += us[r * 64 + e] * WsT[e * 64 + o];
            a2 += xc[r * 64 + e] * WgT[e * 64 + o];
        }
        float g = 1.f / (1.f + expf(-(a1 + a2)));
        op[r * 65 + o] = g * us[r * 64 + o] + (1.f - g) * xc[r * 64 + o];
    }
    __syncthreads();
    int b = (int)(R0 / 4800);
    int rr = (int)(R0 % 4800);
    for (int k2 = 0; k2 < 2; ++k2) {
        int idx = threadIdx.x + (k2 << 8);
        int rloc = idx & 15, oc = idx >> 4;
        float acc = bc11[oc];
        for (int e = 0; e < 64; ++e) acc += op[rloc * 65 + e] * WcT[e * 32 + oc];
        out[(size_t)(b * 32 + oc) * 4800 + rr + rloc] = acc;
    }
}

// ---------------------------------------------------------------------------
extern "C" void kernel_launch(void* const* d_in, const int* in_sizes, int n_in,
                              void* d_out, int out_size, void* d_ws, size_t ws_size,
                              hipStream_t stream)
{
    (void)in_sizes; (void)n_in; (void)out_size; (void)ws_size;
    const float* query = (const float*)d_in[2];
    const float* s0    = (const float*)d_in[3];
    const float* s1    = (const float*)d_in[4];
    const float* sr0   = (const float*)d_in[5];
    const float* sr1   = (const float*)d_in[6];
    const float* Mrg   = (const float*)d_in[7];
    const float* Mor   = (const float*)d_in[8];
    const float* D_S   = (const float*)d_in[9];
    const float* Wc1   = (const float*)d_in[10];
    const float* bc1   = (const float*)d_in[11];
    const float* Wc11  = (const float*)d_in[12];
    const float* bc11  = (const float*)d_in[13];
    const float* Wg    = (const float*)d_in[14];
    const float* bg    = (const float*)d_in[15];
    const float* Wem   = (const float*)d_in[16];
    const float* bem   = (const float*)d_in[17];
    const float* Wq    = (const float*)d_in[18];
    const float* Wk    = (const float*)d_in[19];
    const float* Wv    = (const float*)d_in[20];
    const float* Wfc   = (const float*)d_in[21];
    const float* bfc   = (const float*)d_in[22];
    const float* ln1w  = (const float*)d_in[23];
    const float* ln1b  = (const float*)d_in[24];
    const float* ln2w  = (const float*)d_in[25];
    const float* ln2b  = (const float*)d_in[26];
    const float* Wff1  = (const float*)d_in[27];
    const float* bff1  = (const float*)d_in[28];
    const float* Wff2  = (const float*)d_in[29];
    const float* bff2  = (const float*)d_in[30];
    const float* Wfs   = (const float*)d_in[31];
    const float* bfs   = (const float*)d_in[32];
    const float* Wfg   = (const float*)d_in[33];
    const float* bfg   = (const float*)d_in[34];

    float* ws = (float*)d_ws;
    size_t off = 0;
    auto alloc = [&](size_t n) { float* p = ws + off; off += n; return p; };
    float* q_buf = alloc(4915200);   // (B,N,T,E)
    float* Xc    = alloc(4915200);   // (B,N,T,E) -- doubles as qq pre-CHGCN
    float* x_buf = alloc(4915200);   // doubles as attnO (in-place A1)
    float* US    = alloc(4915200);   // doubles as vv pre-A2
    float* ho    = alloc(2457600);   // (B,C,N,T)
    float* t0    = alloc(2457600);
    float* t1    = alloc(2457600);   // t0+t1 contiguous: doubles as kk
    float* xr    = alloc(393216);    // (B,C,R,T)
    float* tr0   = alloc(393216);
    float* tr1   = alloc(393216);
    float* hr    = alloc(393216);
    float* xsg   = alloc(98304);     // (B,C,G,T)
    float* tg0   = alloc(98304);
    float* tg1   = alloc(98304);
    float* xg0   = alloc(98304);
    float* dsb   = alloc(25600);     // (N,E)
    float* Ag    = alloc(256);
    float* sg0   = alloc(256);
    float* sg1   = alloc(256);

    float* qq    = Xc;               // live only during [k_qkv, k_attn2]
    float* kk    = t0;               // (contiguous with t1)
    float* vv    = US;
    float* attnO = x_buf;

    float* out_main = (float*)d_out;          // (B,C,N,T)
    float* out_xc   = out_main + 2457600;     // (B,C,R,T) final hr
    float* out_xs   = out_main + 2850816;     // (B,C,G,T) final xg

    hipFuncSetAttribute((const void*)k_attn2,
                        hipFuncAttributeMaxDynamicSharedMemorySize, 159872);
    hipFuncSetAttribute((const void*)k_A2n,
                        hipFuncAttributeMaxDynamicSharedMemorySize, 148736);

    hipMemsetAsync(Ag, 0, 256 * sizeof(float), stream);

    // ---- Transformer front (before CHGCN so qq/kk/vv can alias Xc/t0t1/US)
    k_ds<<<400, 64, 0, stream>>>(D_S, Wem, bem, dsb);
    k_conv1<<<800, 256, 0, stream>>>(query, Wc1, bc1, dsb, q_buf);
    k_qkv<<<dim3(384, 7), 256, 0, stream>>>(q_buf, Wq, Wk, Wv, qq, kk, vv);
    k_attn2<<<768, 512, 159872, stream>>>(qq, kk, vv, attnO);
    k_A1<<<2400, 256, 0, stream>>>(attnO, Wfc, bfc, q_buf, ln1w, ln1b, x_buf);
    k_A2n<<<1200, 512, 148736, stream>>>(x_buf, Wff1, bff1, Wff2, bff2,
                                         ln2w, ln2b, US);

    // ---- CHGCN ----
    k_spatial<<<dim3(512, 4), 256, 0, stream>>>(s0, 1, 400, 400, query, nullptr, 1.f, 0, t0);
    k_spatial<<<dim3(512, 4), 256, 0, stream>>>(s1, 1, 400, 400, query, nullptr, 1.f, 0, t1);
    k_gcn_combine<<<800, 256, 0, stream>>>(query, t0, t1, Wg, bg, 400, ho);
    k_spatial<<<dim3(512, 1), 256, 0, stream>>>(Mor, 1, 400, 64, query, nullptr, 1.f, 0, xr);
    k_spatial<<<dim3(512, 1), 256, 0, stream>>>(sr0, 1, 64, 64, xr, nullptr, 1.f, 0, tr0);
    k_spatial<<<dim3(512, 1), 256, 0, stream>>>(sr1, 1, 64, 64, xr, nullptr, 1.f, 0, tr1);
    k_gcn_combine<<<128, 256, 0, stream>>>(xr, tr0, tr1, Wg, bg, 64, hr);
    k_spatial<<<dim3(512, 1), 256, 0, stream>>>(Mrg, 1, 64, 16, xr, nullptr, 1.f, 0, xsg);
    k_agp<<<24, 256, 0, stream>>>(xsg, Ag);
    k_agf<<<1, 64, 0, stream>>>(Ag, sg0, sg1);
    k_spatial<<<dim3(512, 1), 256, 0, stream>>>(sg0, 1, 16, 16, xsg, nullptr, 1.f, 0, tg0);
    k_spatial<<<dim3(512, 1), 256, 0, stream>>>(sg1, 1, 16, 16, xsg, nullptr, 1.f, 0, tg1);
    k_gcn_combine<<<32, 256, 0, stream>>>(xsg, tg0, tg1, Wg, bg, 16, xg0);
    k_spatial<<<dim3(512, 1), 256, 0, stream>>>(Mrg, 0, 16, 64, xg0, hr, 0.5f, 1, hr);
    k_spatial<<<dim3(512, 4), 256, 0, stream>>>(Mor, 0, 64, 400, hr, ho, 0.5f, 1, ho);
    k_spatial<<<dim3(512, 1), 256, 0, stream>>>(Mor, 1, 400, 64, ho, hr, 0.5f, 1, out_xc);
    k_spatial<<<dim3(512, 1), 256, 0, stream>>>(Mrg, 1, 64, 16, out_xc, xg0, 0.5f, 1, out_xs);

    // ---- Tail ----
    k_conv1<<<800, 256, 0, stream>>>(ho, Wc1, bc1, nullptr, Xc);
    k_A3<<<4800, 256, 0, stream>>>(US, Xc, Wfs, bfs, Wfg, bfg, Wc11, bc11, out_main);
}

// Round 5
// 1578.538 us; speedup vs baseline: 2.2341x; 1.2686x over previous
//
#include <hip/hip_runtime.h>

// Dims: B=16 C=32 N=400 T=12 R=64 G=16 E=64 H=2 DH=32 FE=256
#define TT 12

// ---------------------------------------------------------------------------
// Generic spatial contraction over (b,c) batches, vo-chunked via blockIdx.y:
// out[bc, vo, t] = base? base + scale*relu?(acc) : acc
// acc = sum_vi M * in[bc, vi, t]; orientT: M[vi*Vout+vo], else M[vo*Vin+vi]
// ---------------------------------------------------------------------------
__global__ void __launch_bounds__(256) k_spatial(
    const float* __restrict__ M, int orientT, int Vin, int Vout,
    const float* __restrict__ in, const float* __restrict__ base,
    float scale, int do_relu, float* __restrict__ out)
{
    __shared__ float in_lds[400 * TT];
    int bc = blockIdx.x;
    const float* ib = in + (size_t)bc * Vin * TT;
    for (int i = threadIdx.x; i < Vin * TT; i += 256) in_lds[i] = ib[i];
    __syncthreads();
    int chunk = Vout / gridDim.y;
    int vo0 = blockIdx.y * chunk;
    size_t obase = (size_t)bc * Vout * TT;
    for (int idx = threadIdx.x; idx < chunk * TT; idx += 256) {
        int vo = vo0 + idx / TT, t = idx - (idx / TT) * TT;
        float acc = 0.f;
        if (orientT) {
            for (int vi = 0; vi < Vin; ++vi)
                acc += M[(size_t)vi * Vout + vo] * in_lds[vi * TT + t];
        } else {
            const float* Mr = M + (size_t)vo * Vin;
            for (int vi = 0; vi < Vin; ++vi)
                acc += Mr[vi] * in_lds[vi * TT + t];
        }
        if (do_relu) acc = fmaxf(acc, 0.f);
        acc *= scale;
        size_t oi = obase + (size_t)vo * TT + t;
        if (base) acc += base[oi];
        out[oi] = acc;
    }
}

// ---------------------------------------------------------------------------
// GCN combine: out[b,o,v,t] = bias[o] + sum_c W[o,c]*x + W[o,32+c]*t0 + W[o,64+c]*t1
// ---------------------------------------------------------------------------
__global__ void __launch_bounds__(256) k_gcn_combine(
    const float* __restrict__ x, const float* __restrict__ t0in,
    const float* __restrict__ t1in, const float* __restrict__ W,
    const float* __restrict__ bias, int V, float* __restrict__ out)
{
    __shared__ float xs_[96 * 33], t0s[96 * 33], t1s[96 * 33], WT[96 * 32];
    int nb = V / 8;
    int b = blockIdx.x / nb, n0 = (blockIdx.x % nb) * 8;
    for (int l = threadIdx.x; l < 96 * 32; l += 256) {
        int c3 = l >> 5, o = l & 31;
        WT[l] = W[o * 96 + c3];
    }
    for (int l = threadIdx.x; l < 3072; l += 256) {
        int c = l / 96, s = l - c * 96;
        size_t g = ((size_t)((b * 32 + c) * V) + n0 + s / 12) * 12 + (s % 12);
        xs_[s * 33 + c] = x[g];
        t0s[s * 33 + c] = t0in[g];
        t1s[s * 33 + c] = t1in[g];
    }
    __syncthreads();
    for (int idx = threadIdx.x; idx < 3072; idx += 256) {
        int o = idx / 96, s = idx - o * 96;
        float acc = bias[o];
        for (int c = 0; c < 32; ++c) {
            float a = xs_[s * 33 + c] * WT[c * 32 + o];
            float b2 = t0s[s * 33 + c] * WT[(32 + c) * 32 + o];
            float c2 = t1s[s * 33 + c] * WT[(64 + c) * 32 + o];
            acc += a + b2 + c2;
        }
        out[((size_t)(b * 32 + o) * V + n0) * 12 + s] = acc;
    }
}

// ---------------------------------------------------------------------------
// 1x1 conv C->E with layout change (B,C,N,T) -> (B,N,T,E), optional +ds[n,e]
// ---------------------------------------------------------------------------
__global__ void __launch_bounds__(256) k_conv1(
    const float* __restrict__ x, const float* __restrict__ W,
    const float* __restrict__ bias, const float* __restrict__ dsadd,
    float* __restrict__ out)
{
    __shared__ float xs_[96 * 33];
    __shared__ float WT[2048];
    int b = blockIdx.x / 50, n0 = (blockIdx.x % 50) * 8;
    for (int l = threadIdx.x; l < 2048; l += 256) {
        int c = l >> 6, o = l & 63;
        WT[l] = W[o * 32 + c];
    }
    for (int l = threadIdx.x; l < 3072; l += 256) {
        int c = l / 96, s = l - c * 96;
        xs_[s * 33 + c] = x[((size_t)(b * 32 + c) * 400 + n0 + s / 12) * 12 + (s % 12)];
    }
    __syncthreads();
    for (int idx = threadIdx.x; idx < 6144; idx += 256) {
        int s = idx >> 6, o = idx & 63;
        float acc = bias[o];
        for (int c = 0; c < 32; ++c) acc += xs_[s * 33 + c] * WT[(c << 6) + o];
        if (dsadd) acc += dsadd[(n0 + s / 12) * 64 + o];
        out[((size_t)b * 4800 + n0 * 12 + s) * 64 + o] = acc;
    }
}

// ---------------------------------------------------------------------------
// ds[n,e] = sum_m D_S[n,m] * W_embed[e,m] + b_embed[e]
// ---------------------------------------------------------------------------
__global__ void __launch_bounds__(64) k_ds(
    const float* __restrict__ D_S, const float* __restrict__ Wem,
    const float* __restrict__ bem, float* __restrict__ ds)
{
    __shared__ float row[400];
    int n = blockIdx.x;
    for (int i = threadIdx.x; i < 400; i += 64) row[i] = D_S[n * 400 + i];
    __syncthreads();
    int e = threadIdx.x;
    float acc = bem[e];
    const float* we = Wem + (size_t)e * 400;
    for (int m = 0; m < 400; ++m) acc += row[m] * we[m];
    ds[n * 64 + e] = acc;
}

// ---------------------------------------------------------------------------
// Ag partial (reference's mismatched reshape contraction)
// ---------------------------------------------------------------------------
__global__ void __launch_bounds__(256) k_agp(const float* __restrict__ xs,
                                             float* __restrict__ Ag)
{
    __shared__ float A[256 * 17], Bv[256 * 17];
    int i = blockIdx.x * 256 + threadIdx.x;  // < 6144
    int c1 = i / 192, b1 = (i / 12) & 15, t1 = i % 12;
    int t2 = i >> 9, b2 = (i >> 5) & 15, c2 = i & 31;
    for (int g = 0; g < 16; ++g) {
        A[threadIdx.x * 17 + g] = xs[((size_t)(b1 * 32 + c1) * 16 + g) * 12 + t1];
        Bv[threadIdx.x * 17 + g] = xs[((size_t)(b2 * 32 + c2) * 16 + g) * 12 + t2];
    }
    __syncthreads();
    int g1 = threadIdx.x >> 4, g2 = threadIdx.x & 15;
    float acc = 0.f;
    for (int k = 0; k < 256; ++k) acc += A[k * 17 + g1] * Bv[k * 17 + g2];
    atomicAdd(&Ag[threadIdx.x], acc);
}

// ---------------------------------------------------------------------------
// Ag -> relu(Ag-0.5) -> sg0/sg1 softmax(asym_adj)
// ---------------------------------------------------------------------------
__global__ void __launch_bounds__(64) k_agf(const float* __restrict__ Ag,
                                            float* __restrict__ sg0,
                                            float* __restrict__ sg1)
{
    __shared__ float Ar[256], rs[16], cs[16];
    int tid = threadIdx.x;
    for (int l = tid; l < 256; l += 64) Ar[l] = fmaxf(Ag[l] - 0.5f, 0.f);
    __syncthreads();
    if (tid < 16) {
        float r = 0.f, c = 0.f;
        for (int j = 0; j < 16; ++j) { r += Ar[tid * 16 + j]; c += Ar[j * 16 + tid]; }
        rs[tid] = (r > 0.f) ? 1.f / r : 0.f;
        cs[tid] = (c > 0.f) ? 1.f / c : 0.f;
    }
    __syncthreads();
    if (tid < 16) {
        float v[16], m, s;
        m = -1e30f;
        for (int j = 0; j < 16; ++j) { v[j] = Ar[tid * 16 + j] * rs[tid]; m = fmaxf(m, v[j]); }
        s = 0.f;
        for (int j = 0; j < 16; ++j) { v[j] = expf(v[j] - m); s += v[j]; }
        for (int j = 0; j < 16; ++j) sg0[tid * 16 + j] = v[j] / s;
        m = -1e30f;
        for (int j = 0; j < 16; ++j) { v[j] = Ar[j * 16 + tid] * cs[tid]; m = fmaxf(m, v[j]); }
        s = 0.f;
        for (int j = 0; j < 16; ++j) { v[j] = expf(v[j] - m); s += v[j]; }
        for (int j = 0; j < 16; ++j) sg1[tid * 16 + j] = v[j] / s;
    }
}

// ---------------------------------------------------------------------------
// QKV projection: qq/kk/vv[g][n][d] = sum_dd q[b,n,t,h*32+dd]*W{q,k,v}[d][dd]
// g = b*24 + t*2 + h. Grid (384, 7), block 256 (64-row tiles).
// ---------------------------------------------------------------------------
__global__ void __launch_bounds__(256) k_qkv(
    const float* __restrict__ q, const float* __restrict__ Wq,
    const float* __restrict__ Wk, const float* __restrict__ Wv,
    float* __restrict__ qq, float* __restrict__ kk, float* __restrict__ vv)
{
    __shared__ float qs[64 * 33], wqT[1024], wkT[1024], wvT[1024];
    int g = blockIdx.x, n0 = blockIdx.y * 64;
    int b = g / 24, rem = g % 24, t = rem >> 1, h = rem & 1;
    int tid = threadIdx.x;
    for (int i = tid; i < 1024; i += 256) {
        int dd = i >> 5, e = i & 31;
        wqT[i] = Wq[e * 32 + dd];
        wkT[i] = Wk[e * 32 + dd];
        wvT[i] = Wv[e * 32 + dd];
    }
    for (int i = tid; i < 2048; i += 256) {
        int n = i >> 5, dd = i & 31;
        int gn = n0 + n;
        qs[n * 33 + dd] = (gn < 400)
            ? q[((size_t)b * 4800 + gn * 12 + t) * 64 + h * 32 + dd] : 0.f;
    }
    __syncthreads();
    int e = tid & 31, ng = tid >> 5;
    float aq[8], ak[8], av[8];
    #pragma unroll
    for (int k = 0; k < 8; ++k) { aq[k] = 0.f; ak[k] = 0.f; av[k] = 0.f; }
    for (int dd = 0; dd < 32; ++dd) {
        float wq = wqT[dd * 32 + e], wk = wkT[dd * 32 + e], wv = wvT[dd * 32 + e];
        #pragma unroll
        for (int k = 0; k < 8; ++k) {
            float xv = qs[(ng + 8 * k) * 33 + dd];
            aq[k] += xv * wq; ak[k] += xv * wk; av[k] += xv * wv;
        }
    }
    #pragma unroll
    for (int k = 0; k < 8; ++k) {
        int gn = n0 + ng + 8 * k;
        if (gn < 400) {
            size_t a = ((size_t)g * 400 + gn) * 32 + e;
            qq[a] = aq[k]; kk[a] = ak[k]; vv[a] = av[k];
        }
    }
}

// ---------------------------------------------------------------------------
// Attention over nodes, v3. Grid 768 = (b,t,h)x2 row-halves; 1024 thr = 16
// waves = 4 waves/SIMD (vs v2's 2/SIMD). Each wave register-tiles 2 q-rows
// (v2 used 4: e[4][7]+qreg[4][8]+PV pipeline > the 128-VGPR cap the compiler
// insists on -> ~1.7 GB/dispatch scratch spill, measured rounds 2 AND 4;
// launch_bounds(512,2) did NOT lift the cap). 2-row working set ~70 VGPRs.
// Dyn LDS: kkT 32x449 (zero-padded keys) + vv 400x32 + pbuf 16x800
// = 39968 floats = 159872 B (fits 160 KiB, 1 block/CU, 16 waves resident).
// ---------------------------------------------------------------------------
__global__ void __launch_bounds__(1024, 4) k_attn3(
    const float* __restrict__ qq, const float* __restrict__ kk,
    const float* __restrict__ vv, float* __restrict__ attnO)
{
    extern __shared__ float lds[];
    float* kkT = lds;             // 32*449 = 14368
    float* vvs = kkT + 14368;     // 400*32 = 12800
    float* pbuf = vvs + 12800;    // 16 waves * 2*400 = 12800

    int g = blockIdx.x >> 1, rh = blockIdx.x & 1;
    const float* qq_g = qq + (size_t)g * 12800;
    const float* kk_g = kk + (size_t)g * 12800;
    const float* vv_g = vv + (size_t)g * 12800;
    int tid = threadIdx.x;

    for (int i = tid; i < 1568; i += 1024) {         // zero pad cols 400..448
        int d = i / 49, c = i - d * 49;
        kkT[d * 449 + 400 + c] = 0.f;
    }
    for (int i = tid; i < 12800; i += 1024) {
        int k = i >> 5, d = i & 31;
        kkT[d * 449 + k] = kk_g[i];
        vvs[i] = vv_g[i];
    }
    __syncthreads();

    int w = tid >> 6, l = tid & 63;                  // w in 0..15
    float* pw = pbuf + w * 800;
    int b = g / 24, rem = g % 24, t = rem >> 1, h = rem & 1;
    size_t obase = ((size_t)b * 4800 + t) * 64 + h * 32;

    for (int r0 = rh * 200 + w * 2; r0 < rh * 200 + 200; r0 += 32) {
        float e0[7], e1[7];
        #pragma unroll
        for (int j = 0; j < 7; ++j) { e0[j] = 0.f; e1[j] = 0.f; }

        for (int db = 0; db < 4; ++db) {
            float q0[8], q1[8];
            #pragma unroll
            for (int dd = 0; dd < 8; ++dd) {
                q0[dd] = qq_g[(r0 + 0) * 32 + db * 8 + dd];
                q1[dd] = qq_g[(r0 + 1) * 32 + db * 8 + dd];
            }
            #pragma unroll
            for (int j = 0; j < 7; ++j) {
                #pragma unroll
                for (int dd = 0; dd < 8; ++dd) {
                    float kv = kkT[(db * 8 + dd) * 449 + j * 64 + l];
                    e0[j] += q0[dd] * kv;
                    e1[j] += q1[dd] * kv;
                }
            }
        }
        bool ok6 = (l < 16);
        float s0v, s1v;
        {
            if (!ok6) e0[6] = -1e30f;
            float m = e0[0];
            #pragma unroll
            for (int j = 1; j < 7; ++j) m = fmaxf(m, e0[j]);
            #pragma unroll
            for (int off = 32; off; off >>= 1) m = fmaxf(m, __shfl_xor(m, off));
            float ss = 0.f;
            #pragma unroll
            for (int j = 0; j < 7; ++j) {
                e0[j] = __expf((e0[j] - m) * 0.125f);
                ss += e0[j];
            }
            #pragma unroll
            for (int off = 32; off; off >>= 1) ss += __shfl_xor(ss, off);
            s0v = ss;
            #pragma unroll
            for (int j = 0; j < 6; ++j) pw[j * 64 + l] = e0[j];
            if (ok6) pw[384 + l] = e0[6];
        }
        {
            if (!ok6) e1[6] = -1e30f;
            float m = e1[0];
            #pragma unroll
            for (int j = 1; j < 7; ++j) m = fmaxf(m, e1[j]);
            #pragma unroll
            for (int off = 32; off; off >>= 1) m = fmaxf(m, __shfl_xor(m, off));
            float ss = 0.f;
            #pragma unroll
            for (int j = 0; j < 7; ++j) {
                e1[j] = __expf((e1[j] - m) * 0.125f);
                ss += e1[j];
            }
            #pragma unroll
            for (int off = 32; off; off >>= 1) ss += __shfl_xor(ss, off);
            s1v = ss;
            #pragma unroll
            for (int j = 0; j < 6; ++j) pw[400 + j * 64 + l] = e1[j];
            if (ok6) pw[784 + l] = e1[6];
        }
        asm volatile("" ::: "memory");   // wave-private LDS: in-order DS pipe

        int hh = l >> 5, d = l & 31;
        float o0 = 0.f, o1 = 0.f;
        const float* pr0 = pw + hh * 200;
        const float* pr1 = pw + 400 + hh * 200;
        int kb0 = hh * 200;
        for (int kb = 0; kb < 200; kb += 4) {
            float4 p0 = *(const float4*)(pr0 + kb);
            float4 p1 = *(const float4*)(pr1 + kb);
            int k = kb0 + kb;
            float v0 = vvs[(k + 0) * 32 + d];
            float v1 = vvs[(k + 1) * 32 + d];
            float v2 = vvs[(k + 2) * 32 + d];
            float v3 = vvs[(k + 3) * 32 + d];
            o0 += p0.x * v0 + p0.y * v1 + p0.z * v2 + p0.w * v3;
            o1 += p1.x * v0 + p1.y * v1 + p1.z * v2 + p1.w * v3;
        }
        asm volatile("" ::: "memory");
        o0 += __shfl_down(o0, 32);
        o1 += __shfl_down(o1, 32);
        if (l < 32) {
            attnO[obase + (size_t)(r0 + 0) * 768 + d] = o0 / s0v;
            attnO[obase + (size_t)(r0 + 1) * 768 + d] = o1 / s1v;
        }
    }
}

// ---------------------------------------------------------------------------
// A1: x = LN(attnO @ Wfc^T + bfc + q); 32 rows/block (in-place safe per block)
// ---------------------------------------------------------------------------
__global__ void __launch_bounds__(256) k_A1(
    const float* __restrict__ attnO, const float* __restrict__ Wfc,
    const float* __restrict__ bfc, const float* __restrict__ qbuf,
    const float* __restrict__ w1, const float* __restrict__ b1,
    float* __restrict__ xout)
{
    __shared__ float WT[4096], ao[2048], qs[2048];
    size_t r0 = (size_t)blockIdx.x * 32;
    for (int l = threadIdx.x; l < 4096; l += 256) {
        int e = l >> 6, o = l & 63;
        WT[l] = Wfc[o * 64 + e];
    }
    for (int l = threadIdx.x; l < 2048; l += 256) {
        ao[l] = attnO[r0 * 64 + l];
        qs[l] = qbuf[r0 * 64 + l];
    }
    __syncthreads();
    int o = threadIdx.x & 63, w = threadIdx.x >> 6;
    for (int k = 0; k < 8; ++k) {
        int r = w + (k << 2);
        float acc = bfc[o];
        for (int e = 0; e < 64; ++e) acc += ao[r * 64 + e] * WT[e * 64 + o];
        float val = acc + qs[r * 64 + o];
        float sum = val;
        for (int off = 32; off; off >>= 1) sum += __shfl_xor(sum, off);
        float mean = sum * (1.f / 64.f);
        float dv = val - mean;
        float vs = dv * dv;
        for (int off = 32; off; off >>= 1) vs += __shfl_xor(vs, off);
        float inv = rsqrtf(vs * (1.f / 64.f) + 1e-5f);
        xout[(r0 + r) * 64 + o] = dv * inv * w1[o] + b1[o];
    }
}

// ---------------------------------------------------------------------------
// A2 fused FF: US = LN(relu(x@W1^T+b1)@W2^T+b2 + x). 64 rows/block, 512 thr.
// Dyn LDS: xs 64x65 + Wbuf 16384 + fhT 256x65 = 37184 floats = 148736 B
// ---------------------------------------------------------------------------
__global__ void __launch_bounds__(512, 2) k_A2n(
    const float* __restrict__ xin, const float* __restrict__ Wff1,
    const float* __restrict__ bff1, const float* __restrict__ Wff2,
    const float* __restrict__ bff2, const float* __restrict__ w2,
    const float* __restrict__ b2, float* __restrict__ US)
{
    extern __shared__ float lds[];
    float* xs = lds;             // 64*65 = 4160
    float* Wb = xs + 4160;       // 16384
    float* fhT = Wb + 16384;     // 256*65 = 16640
    size_t R0 = (size_t)blockIdx.x * 64;
    int tid = threadIdx.x;
    for (int i = tid; i < 4096; i += 512) {
        int r = i >> 6, e = i & 63;
        xs[r * 65 + e] = xin[(R0 + r) * 64 + e];
    }
    for (int i = tid; i < 16384; i += 512) {
        int e = i >> 8, f = i & 255;
        Wb[i] = Wff1[f * 64 + e];    // W1T[e][f]
    }
    __syncthreads();
    int l = tid & 63, g = tid >> 6;
    {
        float acc[4][8];
        #pragma unroll
        for (int j = 0; j < 4; ++j)
            #pragma unroll
            for (int ri = 0; ri < 8; ++ri) acc[j][ri] = 0.f;
        for (int e = 0; e < 64; ++e) {
            float xr[8];
            #pragma unroll
            for (int ri = 0; ri < 8; ++ri) xr[ri] = xs[(g * 8 + ri) * 65 + e];
            #pragma unroll
            for (int j = 0; j < 4; ++j) {
                float wv = Wb[e * 256 + l + 64 * j];
                #pragma unroll
                for (int ri = 0; ri < 8; ++ri) acc[j][ri] += xr[ri] * wv;
            }
        }
        #pragma unroll
        for (int j = 0; j < 4; ++j) {
            float bb = bff1[l + 64 * j];
            #pragma unroll
            for (int ri = 0; ri < 8; ++ri)
                fhT[(l + 64 * j) * 65 + g * 8 + ri] = fmaxf(acc[j][ri] + bb, 0.f);
        }
    }
    __syncthreads();
    for (int i = tid; i < 16384; i += 512) {
        int f = i >> 6, o = i & 63;
        Wb[i] = Wff2[o * 256 + f];   // W2T[f][o]
    }
    __syncthreads();
    float acc2[8];
    #pragma unroll
    for (int oi = 0; oi < 8; ++oi) acc2[oi] = 0.f;
    for (int f = 0; f < 256; ++f) {
        float fv = fhT[f * 65 + l];
        float4 wa = *(const float4*)(Wb + f * 64 + g * 8);
        float4 wb_ = *(const float4*)(Wb + f * 64 + g * 8 + 4);
        acc2[0] += fv * wa.x;  acc2[1] += fv * wa.y;
        acc2[2] += fv * wa.z;  acc2[3] += fv * wa.w;
        acc2[4] += fv * wb_.x; acc2[5] += fv * wb_.y;
        acc2[6] += fv * wb_.z; acc2[7] += fv * wb_.w;
    }
    __syncthreads();                 // all reads of Wb/fhT done
    float* lnb = Wb;                 // 64*65
    float* mM = Wb + 4160;
    float* mI = Wb + 4224;
    #pragma unroll
    for (int oi = 0; oi < 8; ++oi) {
        int o = g * 8 + oi;
        lnb[l * 65 + o] = acc2[oi] + bff2[o] + xs[l * 65 + o];
    }
    __syncthreads();
    int r = tid >> 3, sb = tid & 7;
    float v[8];
    float sm = 0.f;
    #pragma unroll
    for (int i = 0; i < 8; ++i) { v[i] = lnb[r * 65 + sb + 8 * i]; sm += v[i]; }
    sm += __shfl_xor(sm, 1); sm += __shfl_xor(sm, 2); sm += __shfl_xor(sm, 4);
    float mean = sm * (1.f / 64.f);
    float vs = 0.f;
    #pragma unroll
    for (int i = 0; i < 8; ++i) { float dv = v[i] - mean; vs += dv * dv; }
    vs += __shfl_xor(vs, 1); vs += __shfl_xor(vs, 2); vs += __shfl_xor(vs, 4);
    float inv = rsqrtf(vs * (1.f / 64.f) + 1e-5f);
    if (sb == 0) { mM[r] = mean; mI[r] = inv; }
    __syncthreads();
    for (int i = tid; i < 4096; i += 512) {
        int rr = i >> 6, o = i & 63;
        US[(R0 + rr) * 64 + o] = (lnb[rr * 65 + o] - mM[rr]) * mI[rr] * w2[o] + b2[o];
    }
}

// ---------------------------------------------------------------------------
// A3: gate + blend + final 1x1 conv E->C with transpose to (B,C,N,T)
// ---------------------------------------------------------------------------
__global__ void __launch_bounds__(256) k_A3(
    const float* __restrict__ US, const float* __restrict__ Xc,
    const float* __restrict__ Wfs, const float* __restrict__ bfs,
    const float* __restrict__ Wfg, const float* __restrict__ bfg,
    const float* __restrict__ Wc11, const float* __restrict__ bc11,
    float* __restrict__ out)
{
    __shared__ float us[1024], xc[1024], WsT[4096], WgT[4096], WcT[2048], op[16 * 65];
    size_t R0 = (size_t)blockIdx.x * 16;
    for (int l = threadIdx.x; l < 4096; l += 256) {
        int e = l >> 6, o = l & 63;
        WsT[l] = Wfs[o * 64 + e];
        WgT[l] = Wfg[o * 64 + e];
    }
    for (int l = threadIdx.x; l < 2048; l += 256) {
        int e = l >> 5, oc = l & 31;
        WcT[l] = Wc11[oc * 64 + e];
    }
    for (int l = threadIdx.x; l < 1024; l += 256) {
        us[l] = US[R0 * 64 + l];
        xc[l] = Xc[R0 * 64 + l];
    }
    __syncthreads();
    int o = threadIdx.x & 63, w = threadIdx.x >> 6;
    for (int k = 0; k < 4; ++k) {
        int r = w + (k << 2);
        float a1 = bfs[o], a2 = bfg[o];
        for (int e = 0; e < 64; ++e) {
            a1 += us[r * 64 + e] * WsT[e * 64 + o];
            a2 += xc[r * 64 + e] * WgT[e * 64 + o];
        }
        float g = 1.f / (1.f + expf(-(a1 + a2)));
        op[r * 65 + o] = g * us[r * 64 + o] + (1.f - g) * xc[r * 64 + o];
    }
    __syncthreads();
    int b = (int)(R0 / 4800);
    int rr = (int)(R0 % 4800);
    for (int k2 = 0; k2 < 2; ++k2) {
        int idx = threadIdx.x + (k2 << 8);
        int rloc = idx & 15, oc = idx >> 4;
        float acc = bc11[oc];
        for (int e = 0; e < 64; ++e) acc += op[rloc * 65 + e] * WcT[e * 32 + oc];
        out[(size_t)(b * 32 + oc) * 4800 + rr + rloc] = acc;
    }
}

// ---------------------------------------------------------------------------
extern "C" void kernel_launch(void* const* d_in, const int* in_sizes, int n_in,
                              void* d_out, int out_size, void* d_ws, size_t ws_size,
                              hipStream_t stream)
{
    (void)in_sizes; (void)n_in; (void)out_size; (void)ws_size;
    const float* query = (const float*)d_in[2];
    const float* s0    = (const float*)d_in[3];
    const float* s1    = (const float*)d_in[4];
    const float* sr0   = (const float*)d_in[5];
    const float* sr1   = (const float*)d_in[6];
    const float* Mrg   = (const float*)d_in[7];
    const float* Mor   = (const float*)d_in[8];
    const float* D_S   = (const float*)d_in[9];
    const float* Wc1   = (const float*)d_in[10];
    const float* bc1   = (const float*)d_in[11];
    const float* Wc11  = (const float*)d_in[12];
    const float* bc11  = (const float*)d_in[13];
    const float* Wg    = (const float*)d_in[14];
    const float* bg    = (const float*)d_in[15];
    const float* Wem   = (const float*)d_in[16];
    const float* bem   = (const float*)d_in[17];
    const float* Wq    = (const float*)d_in[18];
    const float* Wk    = (const float*)d_in[19];
    const float* Wv    = (const float*)d_in[20];
    const float* Wfc   = (const float*)d_in[21];
    const float* bfc   = (const float*)d_in[22];
    const float* ln1w  = (const float*)d_in[23];
    const float* ln1b  = (const float*)d_in[24];
    const float* ln2w  = (const float*)d_in[25];
    const float* ln2b  = (const float*)d_in[26];
    const float* Wff1  = (const float*)d_in[27];
    const float* bff1  = (const float*)d_in[28];
    const float* Wff2  = (const float*)d_in[29];
    const float* bff2  = (const float*)d_in[30];
    const float* Wfs   = (const float*)d_in[31];
    const float* bfs   = (const float*)d_in[32];
    const float* Wfg   = (const float*)d_in[33];
    const float* bfg   = (const float*)d_in[34];

    float* ws = (float*)d_ws;
    size_t off = 0;
    auto alloc = [&](size_t n) { float* p = ws + off; off += n; return p; };
    float* q_buf = alloc(4915200);   // (B,N,T,E)
    float* Xc    = alloc(4915200);   // (B,N,T,E) -- doubles as qq pre-CHGCN
    float* x_buf = alloc(4915200);   // doubles as attnO (in-place A1)
    float* US    = alloc(4915200);   // doubles as vv pre-A2
    float* ho    = alloc(2457600);   // (B,C,N,T)
    float* t0    = alloc(2457600);
    float* t1    = alloc(2457600);   // t0+t1 contiguous: doubles as kk
    float* xr    = alloc(393216);    // (B,C,R,T)
    float* tr0   = alloc(393216);
    float* tr1   = alloc(393216);
    float* hr    = alloc(393216);
    float* xsg   = alloc(98304);     // (B,C,G,T)
    float* tg0   = alloc(98304);
    float* tg1   = alloc(98304);
    float* xg0   = alloc(98304);
    float* dsb   = alloc(25600);     // (N,E)
    float* Ag    = alloc(256);
    float* sg0   = alloc(256);
    float* sg1   = alloc(256);

    float* qq    = Xc;               // live only during [k_qkv, k_attn3]
    float* kk    = t0;               // (contiguous with t1)
    float* vv    = US;
    float* attnO = x_buf;

    float* out_main = (float*)d_out;          // (B,C,N,T)
    float* out_xc   = out_main + 2457600;     // (B,C,R,T) final hr
    float* out_xs   = out_main + 2850816;     // (B,C,G,T) final xg

    hipFuncSetAttribute((const void*)k_attn3,
                        hipFuncAttributeMaxDynamicSharedMemorySize, 159872);
    hipFuncSetAttribute((const void*)k_A2n,
                        hipFuncAttributeMaxDynamicSharedMemorySize, 148736);

    hipMemsetAsync(Ag, 0, 256 * sizeof(float), stream);

    // ---- Transformer front (before CHGCN so qq/kk/vv can alias Xc/t0t1/US)
    k_ds<<<400, 64, 0, stream>>>(D_S, Wem, bem, dsb);
    k_conv1<<<800, 256, 0, stream>>>(query, Wc1, bc1, dsb, q_buf);
    k_qkv<<<dim3(384, 7), 256, 0, stream>>>(q_buf, Wq, Wk, Wv, qq, kk, vv);
    k_attn3<<<768, 1024, 159872, stream>>>(qq, kk, vv, attnO);
    k_A1<<<2400, 256, 0, stream>>>(attnO, Wfc, bfc, q_buf, ln1w, ln1b, x_buf);
    k_A2n<<<1200, 512, 148736, stream>>>(x_buf, Wff1, bff1, Wff2, bff2,
                                         ln2w, ln2b, US);

    // ---- CHGCN ----
    k_spatial<<<dim3(512, 4), 256, 0, stream>>>(s0, 1, 400, 400, query, nullptr, 1.f, 0, t0);
    k_spatial<<<dim3(512, 4), 256, 0, stream>>>(s1, 1, 400, 400, query, nullptr, 1.f, 0, t1);
    k_gcn_combine<<<800, 256, 0, stream>>>(query, t0, t1, Wg, bg, 400, ho);
    k_spatial<<<dim3(512, 1), 256, 0, stream>>>(Mor, 1, 400, 64, query, nullptr, 1.f, 0, xr);
    k_spatial<<<dim3(512, 1), 256, 0, stream>>>(sr0, 1, 64, 64, xr, nullptr, 1.f, 0, tr0);
    k_spatial<<<dim3(512, 1), 256, 0, stream>>>(sr1, 1, 64, 64, xr, nullptr, 1.f, 0, tr1);
    k_gcn_combine<<<128, 256, 0, stream>>>(xr, tr0, tr1, Wg, bg, 64, hr);
    k_spatial<<<dim3(512, 1), 256, 0, stream>>>(Mrg, 1, 64, 16, xr, nullptr, 1.f, 0, xsg);
    k_agp<<<24, 256, 0, stream>>>(xsg, Ag);
    k_agf<<<1, 64, 0, stream>>>(Ag, sg0, sg1);
    k_spatial<<<dim3(512, 1), 256, 0, stream>>>(sg0, 1, 16, 16, xsg, nullptr, 1.f, 0, tg0);
    k_spatial<<<dim3(512, 1), 256, 0, stream>>>(sg1, 1, 16, 16, xsg, nullptr, 1.f, 0, tg1);
    k_gcn_combine<<<32, 256, 0, stream>>>(xsg, tg0, tg1, Wg, bg, 16, xg0);
    k_spatial<<<dim3(512, 1), 256, 0, stream>>>(Mrg, 0, 16, 64, xg0, hr, 0.5f, 1, hr);
    k_spatial<<<dim3(512, 4), 256, 0, stream>>>(Mor, 0, 64, 400, hr, ho, 0.5f, 1, ho);
    k_spatial<<<dim3(512, 1), 256, 0, stream>>>(Mor, 1, 400, 64, ho, hr, 0.5f, 1, out_xc);
    k_spatial<<<dim3(512, 1), 256, 0, stream>>>(Mrg, 1, 64, 16, out_xc, xg0, 0.5f, 1, out_xs);

    // ---- Tail ----
    k_conv1<<<800, 256, 0, stream>>>(ho, Wc1, bc1, nullptr, Xc);
    k_A3<<<4800, 256, 0, stream>>>(US, Xc, Wfs, bfs, Wfg, bfg, Wc11, bc11, out_main);
}

// Round 7
// 1434.112 us; speedup vs baseline: 2.4591x; 1.1007x over previous
//
#include <hip/hip_runtime.h>

// Dims: B=16 C=32 N=400 T=12 R=64 G=16 E=64 H=2 DH=32 FE=256
#define TT 12

// ---------------------------------------------------------------------------
// Generic spatial contraction over (b,c) batches, vo-chunked via blockIdx.y
// ---------------------------------------------------------------------------
__global__ void __launch_bounds__(256) k_spatial(
    const float* __restrict__ M, int orientT, int Vin, int Vout,
    const float* __restrict__ in, const float* __restrict__ base,
    float scale, int do_relu, float* __restrict__ out)
{
    __shared__ float in_lds[400 * TT];
    int bc = blockIdx.x;
    const float* ib = in + (size_t)bc * Vin * TT;
    for (int i = threadIdx.x; i < Vin * TT; i += 256) in_lds[i] = ib[i];
    __syncthreads();
    int chunk = Vout / gridDim.y;
    int vo0 = blockIdx.y * chunk;
    size_t obase = (size_t)bc * Vout * TT;
    for (int idx = threadIdx.x; idx < chunk * TT; idx += 256) {
        int vo = vo0 + idx / TT, t = idx - (idx / TT) * TT;
        float acc = 0.f;
        if (orientT) {
            for (int vi = 0; vi < Vin; ++vi)
                acc += M[(size_t)vi * Vout + vo] * in_lds[vi * TT + t];
        } else {
            const float* Mr = M + (size_t)vo * Vin;
            for (int vi = 0; vi < Vin; ++vi)
                acc += Mr[vi] * in_lds[vi * TT + t];
        }
        if (do_relu) acc = fmaxf(acc, 0.f);
        acc *= scale;
        size_t oi = obase + (size_t)vo * TT + t;
        if (base) acc += base[oi];
        out[oi] = acc;
    }
}

// ---------------------------------------------------------------------------
// GCN combine
// ---------------------------------------------------------------------------
__global__ void __launch_bounds__(256) k_gcn_combine(
    const float* __restrict__ x, const float* __restrict__ t0in,
    const float* __restrict__ t1in, const float* __restrict__ W,
    const float* __restrict__ bias, int V, float* __restrict__ out)
{
    __shared__ float xs_[96 * 33], t0s[96 * 33], t1s[96 * 33], WT[96 * 32];
    int nb = V / 8;
    int b = blockIdx.x / nb, n0 = (blockIdx.x % nb) * 8;
    for (int l = threadIdx.x; l < 96 * 32; l += 256) {
        int c3 = l >> 5, o = l & 31;
        WT[l] = W[o * 96 + c3];
    }
    for (int l = threadIdx.x; l < 3072; l += 256) {
        int c = l / 96, s = l - c * 96;
        size_t g = ((size_t)((b * 32 + c) * V) + n0 + s / 12) * 12 + (s % 12);
        xs_[s * 33 + c] = x[g];
        t0s[s * 33 + c] = t0in[g];
        t1s[s * 33 + c] = t1in[g];
    }
    __syncthreads();
    for (int idx = threadIdx.x; idx < 3072; idx += 256) {
        int o = idx / 96, s = idx - o * 96;
        float acc = bias[o];
        for (int c = 0; c < 32; ++c) {
            float a = xs_[s * 33 + c] * WT[c * 32 + o];
            float b2 = t0s[s * 33 + c] * WT[(32 + c) * 32 + o];
            float c2 = t1s[s * 33 + c] * WT[(64 + c) * 32 + o];
            acc += a + b2 + c2;
        }
        out[((size_t)(b * 32 + o) * V + n0) * 12 + s] = acc;
    }
}

// ---------------------------------------------------------------------------
// 1x1 conv C->E with layout change (B,C,N,T) -> (B,N,T,E), optional +ds[n,e]
// ---------------------------------------------------------------------------
__global__ void __launch_bounds__(256) k_conv1(
    const float* __restrict__ x, const float* __restrict__ W,
    const float* __restrict__ bias, const float* __restrict__ dsadd,
    float* __restrict__ out)
{
    __shared__ float xs_[96 * 33];
    __shared__ float WT[2048];
    int b = blockIdx.x / 50, n0 = (blockIdx.x % 50) * 8;
    for (int l = threadIdx.x; l < 2048; l += 256) {
        int c = l >> 6, o = l & 63;
        WT[l] = W[o * 32 + c];
    }
    for (int l = threadIdx.x; l < 3072; l += 256) {
        int c = l / 96, s = l - c * 96;
        xs_[s * 33 + c] = x[((size_t)(b * 32 + c) * 400 + n0 + s / 12) * 12 + (s % 12)];
    }
    __syncthreads();
    for (int idx = threadIdx.x; idx < 6144; idx += 256) {
        int s = idx >> 6, o = idx & 63;
        float acc = bias[o];
        for (int c = 0; c < 32; ++c) acc += xs_[s * 33 + c] * WT[(c << 6) + o];
        if (dsadd) acc += dsadd[(n0 + s / 12) * 64 + o];
        out[((size_t)b * 4800 + n0 * 12 + s) * 64 + o] = acc;
    }
}

// ---------------------------------------------------------------------------
// ds[n,e] = sum_m D_S[n,m] * W_embed[e,m] + b_embed[e]
// ---------------------------------------------------------------------------
__global__ void __launch_bounds__(64) k_ds(
    const float* __restrict__ D_S, const float* __restrict__ Wem,
    const float* __restrict__ bem, float* __restrict__ ds)
{
    __shared__ float row[400];
    int n = blockIdx.x;
    for (int i = threadIdx.x; i < 400; i += 64) row[i] = D_S[n * 400 + i];
    __syncthreads();
    int e = threadIdx.x;
    float acc = bem[e];
    const float* we = Wem + (size_t)e * 400;
    for (int m = 0; m < 400; ++m) acc += row[m] * we[m];
    ds[n * 64 + e] = acc;
}

// ---------------------------------------------------------------------------
// Ag partial (reference's mismatched reshape contraction)
// ---------------------------------------------------------------------------
__global__ void __launch_bounds__(256) k_agp(const float* __restrict__ xs,
                                             float* __restrict__ Ag)
{
    __shared__ float A[256 * 17], Bv[256 * 17];
    int i = blockIdx.x * 256 + threadIdx.x;  // < 6144
    int c1 = i / 192, b1 = (i / 12) & 15, t1 = i % 12;
    int t2 = i >> 9, b2 = (i >> 5) & 15, c2 = i & 31;
    for (int g = 0; g < 16; ++g) {
        A[threadIdx.x * 17 + g] = xs[((size_t)(b1 * 32 + c1) * 16 + g) * 12 + t1];
        Bv[threadIdx.x * 17 + g] = xs[((size_t)(b2 * 32 + c2) * 16 + g) * 12 + t2];
    }
    __syncthreads();
    int g1 = threadIdx.x >> 4, g2 = threadIdx.x & 15;
    float acc = 0.f;
    for (int k = 0; k < 256; ++k) acc += A[k * 17 + g1] * Bv[k * 17 + g2];
    atomicAdd(&Ag[threadIdx.x], acc);
}

// ---------------------------------------------------------------------------
// Ag -> relu(Ag-0.5) -> sg0/sg1 softmax(asym_adj)
// ---------------------------------------------------------------------------
__global__ void __launch_bounds__(64) k_agf(const float* __restrict__ Ag,
                                            float* __restrict__ sg0,
                                            float* __restrict__ sg1)
{
    __shared__ float Ar[256], rs[16], cs[16];
    int tid = threadIdx.x;
    for (int l = tid; l < 256; l += 64) Ar[l] = fmaxf(Ag[l] - 0.5f, 0.f);
    __syncthreads();
    if (tid < 16) {
        float r = 0.f, c = 0.f;
        for (int j = 0; j < 16; ++j) { r += Ar[tid * 16 + j]; c += Ar[j * 16 + tid]; }
        rs[tid] = (r > 0.f) ? 1.f / r : 0.f;
        cs[tid] = (c > 0.f) ? 1.f / c : 0.f;
    }
    __syncthreads();
    if (tid < 16) {
        float v[16], m, s;
        m = -1e30f;
        for (int j = 0; j < 16; ++j) { v[j] = Ar[tid * 16 + j] * rs[tid]; m = fmaxf(m, v[j]); }
        s = 0.f;
        for (int j = 0; j < 16; ++j) { v[j] = expf(v[j] - m); s += v[j]; }
        for (int j = 0; j < 16; ++j) sg0[tid * 16 + j] = v[j] / s;
        m = -1e30f;
        for (int j = 0; j < 16; ++j) { v[j] = Ar[j * 16 + tid] * cs[tid]; m = fmaxf(m, v[j]); }
        s = 0.f;
        for (int j = 0; j < 16; ++j) { v[j] = expf(v[j] - m); s += v[j]; }
        for (int j = 0; j < 16; ++j) sg1[tid * 16 + j] = v[j] / s;
    }
}

// ---------------------------------------------------------------------------
// QKV projection
// ---------------------------------------------------------------------------
__global__ void __launch_bounds__(256) k_qkv(
    const float* __restrict__ q, const float* __restrict__ Wq,
    const float* __restrict__ Wk, const float* __restrict__ Wv,
    float* __restrict__ qq, float* __restrict__ kk, float* __restrict__ vv)
{
    __shared__ float qs[64 * 33], wqT[1024], wkT[1024], wvT[1024];
    int g = blockIdx.x, n0 = blockIdx.y * 64;
    int b = g / 24, rem = g % 24, t = rem >> 1, h = rem & 1;
    int tid = threadIdx.x;
    for (int i = tid; i < 1024; i += 256) {
        int dd = i >> 5, e = i & 31;
        wqT[i] = Wq[e * 32 + dd];
        wkT[i] = Wk[e * 32 + dd];
        wvT[i] = Wv[e * 32 + dd];
    }
    for (int i = tid; i < 2048; i += 256) {
        int n = i >> 5, dd = i & 31;
        int gn = n0 + n;
        qs[n * 33 + dd] = (gn < 400)
            ? q[((size_t)b * 4800 + gn * 12 + t) * 64 + h * 32 + dd] : 0.f;
    }
    __syncthreads();
    int e = tid & 31, ng = tid >> 5;
    float aq[8], ak[8], av[8];
    #pragma unroll
    for (int k = 0; k < 8; ++k) { aq[k] = 0.f; ak[k] = 0.f; av[k] = 0.f; }
    for (int dd = 0; dd < 32; ++dd) {
        float wq = wqT[dd * 32 + e], wk = wkT[dd * 32 + e], wv = wvT[dd * 32 + e];
        #pragma unroll
        for (int k = 0; k < 8; ++k) {
            float xv = qs[(ng + 8 * k) * 33 + dd];
            aq[k] += xv * wq; ak[k] += xv * wk; av[k] += xv * wv;
        }
    }
    #pragma unroll
    for (int k = 0; k < 8; ++k) {
        int gn = n0 + ng + 8 * k;
        if (gn < 400) {
            size_t a = ((size_t)g * 400 + gn) * 32 + e;
            qq[a] = aq[k]; kk[a] = ak[k]; vv[a] = av[k];
        }
    }
}

// ---------------------------------------------------------------------------
// Attention over nodes, v3 (spill-free 2 rows/wave; verified round 5).
// ---------------------------------------------------------------------------
__global__ void __launch_bounds__(1024, 4) k_attn3(
    const float* __restrict__ qq, const float* __restrict__ kk,
    const float* __restrict__ vv, float* __restrict__ attnO)
{
    extern __shared__ float lds[];
    float* kkT = lds;             // 32*449 = 14368
    float* vvs = kkT + 14368;     // 400*32 = 12800
    float* pbuf = vvs + 12800;    // 16 waves * 2*400 = 12800

    int g = blockIdx.x >> 1, rh = blockIdx.x & 1;
    const float* qq_g = qq + (size_t)g * 12800;
    const float* kk_g = kk + (size_t)g * 12800;
    const float* vv_g = vv + (size_t)g * 12800;
    int tid = threadIdx.x;

    for (int i = tid; i < 1568; i += 1024) {         // zero pad cols 400..448
        int d = i / 49, c = i - d * 49;
        kkT[d * 449 + 400 + c] = 0.f;
    }
    for (int i = tid; i < 12800; i += 1024) {
        int k = i >> 5, d = i & 31;
        kkT[d * 449 + k] = kk_g[i];
        vvs[i] = vv_g[i];
    }
    __syncthreads();

    int w = tid >> 6, l = tid & 63;                  // w in 0..15
    float* pw = pbuf + w * 800;
    int b = g / 24, rem = g % 24, t = rem >> 1, h = rem & 1;
    size_t obase = ((size_t)b * 4800 + t) * 64 + h * 32;

    for (int r0 = rh * 200 + w * 2; r0 < rh * 200 + 200; r0 += 32) {
        float e0[7], e1[7];
        #pragma unroll
        for (int j = 0; j < 7; ++j) { e0[j] = 0.f; e1[j] = 0.f; }

        for (int db = 0; db < 4; ++db) {
            float q0[8], q1[8];
            #pragma unroll
            for (int dd = 0; dd < 8; ++dd) {
                q0[dd] = qq_g[(r0 + 0) * 32 + db * 8 + dd];
                q1[dd] = qq_g[(r0 + 1) * 32 + db * 8 + dd];
            }
            #pragma unroll
            for (int j = 0; j < 7; ++j) {
                #pragma unroll
                for (int dd = 0; dd < 8; ++dd) {
                    float kv = kkT[(db * 8 + dd) * 449 + j * 64 + l];
                    e0[j] += q0[dd] * kv;
                    e1[j] += q1[dd] * kv;
                }
            }
        }
        bool ok6 = (l < 16);
        float s0v, s1v;
        {
            if (!ok6) e0[6] = -1e30f;
            float m = e0[0];
            #pragma unroll
            for (int j = 1; j < 7; ++j) m = fmaxf(m, e0[j]);
            #pragma unroll
            for (int off = 32; off; off >>= 1) m = fmaxf(m, __shfl_xor(m, off));
            float ss = 0.f;
            #pragma unroll
            for (int j = 0; j < 7; ++j) {
                e0[j] = __expf((e0[j] - m) * 0.125f);
                ss += e0[j];
            }
            #pragma unroll
            for (int off = 32; off; off >>= 1) ss += __shfl_xor(ss, off);
            s0v = ss;
            #pragma unroll
            for (int j = 0; j < 6; ++j) pw[j * 64 + l] = e0[j];
            if (ok6) pw[384 + l] = e0[6];
        }
        {
            if (!ok6) e1[6] = -1e30f;
            float m = e1[0];
            #pragma unroll
            for (int j = 1; j < 7; ++j) m = fmaxf(m, e1[j]);
            #pragma unroll
            for (int off = 32; off; off >>= 1) m = fmaxf(m, __shfl_xor(m, off));
            float ss = 0.f;
            #pragma unroll
            for (int j = 0; j < 7; ++j) {
                e1[j] = __expf((e1[j] - m) * 0.125f);
                ss += e1[j];
            }
            #pragma unroll
            for (int off = 32; off; off >>= 1) ss += __shfl_xor(ss, off);
            s1v = ss;
            #pragma unroll
            for (int j = 0; j < 6; ++j) pw[400 + j * 64 + l] = e1[j];
            if (ok6) pw[784 + l] = e1[6];
        }
        asm volatile("" ::: "memory");   // wave-private LDS: in-order DS pipe

        int hh = l >> 5, d = l & 31;
        float o0 = 0.f, o1 = 0.f;
        const float* pr0 = pw + hh * 200;
        const float* pr1 = pw + 400 + hh * 200;
        int kb0 = hh * 200;
        for (int kb = 0; kb < 200; kb += 4) {
            float4 p0 = *(const float4*)(pr0 + kb);
            float4 p1 = *(const float4*)(pr1 + kb);
            int k = kb0 + kb;
            float v0 = vvs[(k + 0) * 32 + d];
            float v1 = vvs[(k + 1) * 32 + d];
            float v2 = vvs[(k + 2) * 32 + d];
            float v3 = vvs[(k + 3) * 32 + d];
            o0 += p0.x * v0 + p0.y * v1 + p0.z * v2 + p0.w * v3;
            o1 += p1.x * v0 + p1.y * v1 + p1.z * v2 + p1.w * v3;
        }
        asm volatile("" ::: "memory");
        o0 += __shfl_down(o0, 32);
        o1 += __shfl_down(o1, 32);
        if (l < 32) {
            attnO[obase + (size_t)(r0 + 0) * 768 + d] = o0 / s0v;
            attnO[obase + (size_t)(r0 + 1) * 768 + d] = o1 / s1v;
        }
    }
}

// ---------------------------------------------------------------------------
// A1 v2: x = LN(attnO @ Wfc^T + bfc + q). 64 rows/block, grid 1200.
// Register-tiled 4x4 (round-5 A3 profile: old per-element loop was 2 LDS b32
// per 1 FMA, DS-latency-bound at 24% VALUBusy). b128 loads -> 8 FMA/DS.
// LDS: WT 64x65 + ao 64x65 + qs 64x65 = 49920 B (3 blocks/CU).
// ---------------------------------------------------------------------------
__global__ void __launch_bounds__(256) k_A1n(
    const float* __restrict__ attnO, const float* __restrict__ Wfc,
    const float* __restrict__ bfc, const float* __restrict__ qbuf,
    const float* __restrict__ w1, const float* __restrict__ b1,
    float* __restrict__ xout)
{
    __shared__ float WT[64 * 65], ao[64 * 65], qs[64 * 65];
    size_t R0 = (size_t)blockIdx.x * 64;
    int tid = threadIdx.x;
    for (int l = tid; l < 4096; l += 256) {       // WT[e][o] = Wfc[o][e]
        int o = l >> 6, e = l & 63;               // coalesced read; pad-65 write
        WT[e * 65 + o] = Wfc[l];
    }
    for (int i = tid; i < 1024; i += 256) {       // stage rows as float4
        int r = i >> 4, c4 = (i & 15) * 4;
        *(float4*)(ao + r * 65 + c4) = *(const float4*)(attnO + (R0 + r) * 64 + c4);
        *(float4*)(qs + r * 65 + c4) = *(const float4*)(qbuf + (R0 + r) * 64 + c4);
    }
    __syncthreads();

    int oj = tid & 15, ri = tid >> 4;             // 4x4 tile: rows 4ri.., cols 4oj..
    float acc[4][4];
    #pragma unroll
    for (int rr = 0; rr < 4; ++rr)
        #pragma unroll
        for (int cc = 0; cc < 4; ++cc) acc[rr][cc] = 0.f;

    for (int eb = 0; eb < 16; ++eb) {
        float w[4][4], u[4][4];
        #pragma unroll
        for (int k = 0; k < 4; ++k) {
            float4 t = *(const float4*)(WT + (eb * 4 + k) * 65 + 4 * oj);
            w[k][0] = t.x; w[k][1] = t.y; w[k][2] = t.z; w[k][3] = t.w;
        }
        #pragma unroll
        for (int rr = 0; rr < 4; ++rr) {
            float4 t = *(const float4*)(ao + (4 * ri + rr) * 65 + eb * 4);
            u[rr][0] = t.x; u[rr][1] = t.y; u[rr][2] = t.z; u[rr][3] = t.w;
        }
        #pragma unroll
        for (int rr = 0; rr < 4; ++rr)
            #pragma unroll
            for (int k = 0; k < 4; ++k) {
                float uv = u[rr][k];
                acc[rr][0] += uv * w[k][0];
                acc[rr][1] += uv * w[k][1];
                acc[rr][2] += uv * w[k][2];
                acc[rr][3] += uv * w[k][3];
            }
    }
    // val = acc + bias + q  -> store into qs (each element owned by its thread)
    float bf[4];
    #pragma unroll
    for (int cc = 0; cc < 4; ++cc) bf[cc] = bfc[4 * oj + cc];
    #pragma unroll
    for (int rr = 0; rr < 4; ++rr)
        #pragma unroll
        for (int cc = 0; cc < 4; ++cc) {
            int r = 4 * ri + rr, o = 4 * oj + cc;
            qs[r * 65 + o] += acc[rr][cc] + bf[cc];
        }
    __syncthreads();
    // LayerNorm: 4 threads per row
    int r = tid >> 2, sb = tid & 3;
    float vals[16];
    float sm = 0.f;
    #pragma unroll
    for (int i = 0; i < 4; ++i) {
        float4 t = *(const float4*)(qs + r * 65 + sb * 16 + 4 * i);
        vals[4 * i + 0] = t.x; vals[4 * i + 1] = t.y;
        vals[4 * i + 2] = t.z; vals[4 * i + 3] = t.w;
        sm += t.x + t.y + t.z + t.w;
    }
    sm += __shfl_xor(sm, 1); sm += __shfl_xor(sm, 2);
    float mean = sm * (1.f / 64.f);
    float vs = 0.f;
    #pragma unroll
    for (int i = 0; i < 16; ++i) { float dv = vals[i] - mean; vs += dv * dv; }
    vs += __shfl_xor(vs, 1); vs += __shfl_xor(vs, 2);
    float inv = rsqrtf(vs * (1.f / 64.f) + 1e-5f);
    #pragma unroll
    for (int i = 0; i < 16; ++i) {
        int o = sb * 16 + i;
        xout[(R0 + r) * 64 + o] = (vals[i] - mean) * inv * w1[o] + b1[o];
    }
}

// ---------------------------------------------------------------------------
// A2 fused FF (unchanged)
// ---------------------------------------------------------------------------
__global__ void __launch_bounds__(512, 2) k_A2n(
    const float* __restrict__ xin, const float* __restrict__ Wff1,
    const float* __restrict__ bff1, const float* __restrict__ Wff2,
    const float* __restrict__ bff2, const float* __restrict__ w2,
    const float* __restrict__ b2, float* __restrict__ US)
{
    extern __shared__ float lds[];
    float* xs = lds;             // 64*65 = 4160
    float* Wb = xs + 4160;       // 16384
    float* fhT = Wb + 16384;     // 256*65 = 16640
    size_t R0 = (size_t)blockIdx.x * 64;
    int tid = threadIdx.x;
    for (int i = tid; i < 4096; i += 512) {
        int r = i >> 6, e = i & 63;
        xs[r * 65 + e] = xin[(R0 + r) * 64 + e];
    }
    for (int i = tid; i < 16384; i += 512) {
        int e = i >> 8, f = i & 255;
        Wb[i] = Wff1[f * 64 + e];    // W1T[e][f]
    }
    __syncthreads();
    int l = tid & 63, g = tid >> 6;
    {
        float acc[4][8];
        #pragma unroll
        for (int j = 0; j < 4; ++j)
            #pragma unroll
            for (int ri = 0; ri < 8; ++ri) acc[j][ri] = 0.f;
        for (int e = 0; e < 64; ++e) {
            float xr[8];
            #pragma unroll
            for (int ri = 0; ri < 8; ++ri) xr[ri] = xs[(g * 8 + ri) * 65 + e];
            #pragma unroll
            for (int j = 0; j < 4; ++j) {
                float wv = Wb[e * 256 + l + 64 * j];
                #pragma unroll
                for (int ri = 0; ri < 8; ++ri) acc[j][ri] += xr[ri] * wv;
            }
        }
        #pragma unroll
        for (int j = 0; j < 4; ++j) {
            float bb = bff1[l + 64 * j];
            #pragma unroll
            for (int ri = 0; ri < 8; ++ri)
                fhT[(l + 64 * j) * 65 + g * 8 + ri] = fmaxf(acc[j][ri] + bb, 0.f);
        }
    }
    __syncthreads();
    for (int i = tid; i < 16384; i += 512) {
        int f = i >> 6, o = i & 63;
        Wb[i] = Wff2[o * 256 + f];   // W2T[f][o]
    }
    __syncthreads();
    float acc2[8];
    #pragma unroll
    for (int oi = 0; oi < 8; ++oi) acc2[oi] = 0.f;
    for (int f = 0; f < 256; ++f) {
        float fv = fhT[f * 65 + l];
        float4 wa = *(const float4*)(Wb + f * 64 + g * 8);
        float4 wb_ = *(const float4*)(Wb + f * 64 + g * 8 + 4);
        acc2[0] += fv * wa.x;  acc2[1] += fv * wa.y;
        acc2[2] += fv * wa.z;  acc2[3] += fv * wa.w;
        acc2[4] += fv * wb_.x; acc2[5] += fv * wb_.y;
        acc2[6] += fv * wb_.z; acc2[7] += fv * wb_.w;
    }
    __syncthreads();
    float* lnb = Wb;                 // 64*65
    float* mM = Wb + 4160;
    float* mI = Wb + 4224;
    #pragma unroll
    for (int oi = 0; oi < 8; ++oi) {
        int o = g * 8 + oi;
        lnb[l * 65 + o] = acc2[oi] + bff2[o] + xs[l * 65 + o];
    }
    __syncthreads();
    int r = tid >> 3, sb = tid & 7;
    float v[8];
    float sm = 0.f;
    #pragma unroll
    for (int i = 0; i < 8; ++i) { v[i] = lnb[r * 65 + sb + 8 * i]; sm += v[i]; }
    sm += __shfl_xor(sm, 1); sm += __shfl_xor(sm, 2); sm += __shfl_xor(sm, 4);
    float mean = sm * (1.f / 64.f);
    float vs = 0.f;
    #pragma unroll
    for (int i = 0; i < 8; ++i) { float dv = v[i] - mean; vs += dv * dv; }
    vs += __shfl_xor(vs, 1); vs += __shfl_xor(vs, 2); vs += __shfl_xor(vs, 4);
    float inv = rsqrtf(vs * (1.f / 64.f) + 1e-5f);
    if (sb == 0) { mM[r] = mean; mI[r] = inv; }
    __syncthreads();
    for (int i = tid; i < 4096; i += 512) {
        int rr = i >> 6, o = i & 63;
        US[(R0 + rr) * 64 + o] = (lnb[rr * 65 + o] - mM[rr]) * mI[rr] * w2[o] + b2[o];
    }
}

// ---------------------------------------------------------------------------
// A3 v2: gate + blend + final conv. 64 rows/block, grid 1200, 4x4 reg tile.
// Round-5 profile of old k_A3: 292 us, VALUBusy 24%, Occ 11% -- DS-bound at
// 0.5 FMA/DS with 40KB weight staging per 16 rows. Now: b128 dual-operand
// loads (8 FMA/DS), staging amortized 4x. Dyn LDS: WsT/WgT 64x65, WcT 64x33,
// us/xc 64x65 = 18752 floats = 75008 B (2 blocks/CU).
// ---------------------------------------------------------------------------
__global__ void __launch_bounds__(256) k_A3n(
    const float* __restrict__ US, const float* __restrict__ Xc,
    const float* __restrict__ Wfs, const float* __restrict__ bfs,
    const float* __restrict__ Wfg, const float* __restrict__ bfg,
    const float* __restrict__ Wc11, const float* __restrict__ bc11,
    float* __restrict__ out)
{
    extern __shared__ float lds[];
    float* WsT = lds;            // 64*65
    float* WgT = WsT + 4160;     // 64*65
    float* WcT = WgT + 4160;     // 64*33
    float* us  = WcT + 2112;     // 64*65   (becomes op after gate)
    float* xc  = us + 4160;      // 64*65
    size_t R0 = (size_t)blockIdx.x * 64;
    int tid = threadIdx.x;
    for (int l = tid; l < 4096; l += 256) {       // transpose with pad-65
        int o = l >> 6, e = l & 63;
        WsT[e * 65 + o] = Wfs[l];
        WgT[e * 65 + o] = Wfg[l];
    }
    for (int l = tid; l < 2048; l += 256) {       // Wc11[oc][e] -> WcT[e][oc], pad-33
        int oc = l >> 6, e = l & 63;
        WcT[e * 33 + oc] = Wc11[l];
    }
    for (int i = tid; i < 1024; i += 256) {
        int r = i >> 4, c4 = (i & 15) * 4;
        *(float4*)(us + r * 65 + c4) = *(const float4*)(US + (R0 + r) * 64 + c4);
        *(float4*)(xc + r * 65 + c4) = *(const float4*)(Xc + (R0 + r) * 64 + c4);
    }
    __syncthreads();

    int oj = tid & 15, ri = tid >> 4;
    float a1[4][4], a2[4][4];
    #pragma unroll
    for (int rr = 0; rr < 4; ++rr)
        #pragma unroll
        for (int cc = 0; cc < 4; ++cc) { a1[rr][cc] = 0.f; a2[rr][cc] = 0.f; }

    for (int eb = 0; eb < 16; ++eb) {
        {   // us @ Wfs
            float w[4][4], u[4][4];
            #pragma unroll
            for (int k = 0; k < 4; ++k) {
                float4 t = *(const float4*)(WsT + (eb * 4 + k) * 65 + 4 * oj);
                w[k][0] = t.x; w[k][1] = t.y; w[k][2] = t.z; w[k][3] = t.w;
            }
            #pragma unroll
            for (int rr = 0; rr < 4; ++rr) {
                float4 t = *(const float4*)(us + (4 * ri + rr) * 65 + eb * 4);
                u[rr][0] = t.x; u[rr][1] = t.y; u[rr][2] = t.z; u[rr][3] = t.w;
            }
            #pragma unroll
            for (int rr = 0; rr < 4; ++rr)
                #pragma unroll
                for (int k = 0; k < 4; ++k) {
                    float uv = u[rr][k];
                    a1[rr][0] += uv * w[k][0];
                    a1[rr][1] += uv * w[k][1];
                    a1[rr][2] += uv * w[k][2];
                    a1[rr][3] += uv * w[k][3];
                }
        }
        {   // xc @ Wfg
            float w[4][4], u[4][4];
            #pragma unroll
            for (int k = 0; k < 4; ++k) {
                float4 t = *(const float4*)(WgT + (eb * 4 + k) * 65 + 4 * oj);
                w[k][0] = t.x; w[k][1] = t.y; w[k][2] = t.z; w[k][3] = t.w;
            }
            #pragma unroll
            for (int rr = 0; rr < 4; ++rr) {
                float4 t = *(const float4*)(xc + (4 * ri + rr) * 65 + eb * 4);
                u[rr][0] = t.x; u[rr][1] = t.y; u[rr][2] = t.z; u[rr][3] = t.w;
            }
            #pragma unroll
            for (int rr = 0; rr < 4; ++rr)
                #pragma unroll
                for (int k = 0; k < 4; ++k) {
                    float uv = u[rr][k];
                    a2[rr][0] += uv * w[k][0];
                    a2[rr][1] += uv * w[k][1];
                    a2[rr][2] += uv * w[k][2];
                    a2[rr][3] += uv * w[k][3];
                }
        }
    }
    __syncthreads();                  // all matvec reads of us/xc complete
    float bs[4], bg2[4];
    #pragma unroll
    for (int cc = 0; cc < 4; ++cc) { bs[cc] = bfs[4 * oj + cc]; bg2[cc] = bfg[4 * oj + cc]; }
    #pragma unroll
    for (int rr = 0; rr < 4; ++rr)
        #pragma unroll
        for (int cc = 0; cc < 4; ++cc) {
            int r = 4 * ri + rr, o = 4 * oj + cc;
            float gg = 1.f / (1.f + __expf(-(a1[rr][cc] + bs[cc] + a2[rr][cc] + bg2[cc])));
            float uv = us[r * 65 + o], xv = xc[r * 65 + o];
            us[r * 65 + o] = gg * uv + (1.f - gg) * xv;   // op
        }
    __syncthreads();

    // conv E->C: out[oc] = bc11[oc] + sum_e op[r][e] * WcT[e][oc]
    int ocj = tid & 7, rg = tid >> 3;         // 4 oc x 2 rows per thread
    float c2[2][4];
    #pragma unroll
    for (int rr = 0; rr < 2; ++rr)
        #pragma unroll
        for (int cc = 0; cc < 4; ++cc) c2[rr][cc] = bc11[4 * ocj + cc];
    for (int eb = 0; eb < 16; ++eb) {
        float w[4][4], p[2][4];
        #pragma unroll
        for (int k = 0; k < 4; ++k) {
            float4 t = *(const float4*)(WcT + (eb * 4 + k) * 33 + 4 * ocj);
            w[k][0] = t.x; w[k][1] = t.y; w[k][2] = t.z; w[k][3] = t.w;
        }
        #pragma unroll
        for (int rr = 0; rr < 2; ++rr) {
            float4 t = *(const float4*)(us + (2 * rg + rr) * 65 + eb * 4);
            p[rr][0] = t.x; p[rr][1] = t.y; p[rr][2] = t.z; p[rr][3] = t.w;
        }
        #pragma unroll
        for (int rr = 0; rr < 2; ++rr)
            #pragma unroll
            for (int k = 0; k < 4; ++k) {
                float pv = p[rr][k];
                c2[rr][0] += pv * w[k][0];
                c2[rr][1] += pv * w[k][1];
                c2[rr][2] += pv * w[k][2];
                c2[rr][3] += pv * w[k][3];
            }
    }
    int b = (int)(R0 / 4800);
    int rr0 = (int)(R0 % 4800);
    #pragma unroll
    for (int cc = 0; cc < 4; ++cc)
        #pragma unroll
        for (int rr = 0; rr < 2; ++rr)
            out[(size_t)(b * 32 + 4 * ocj + cc) * 4800 + rr0 + 2 * rg + rr] = c2[rr][cc];
}

// ---------------------------------------------------------------------------
extern "C" void kernel_launch(void* const* d_in, const int* in_sizes, int n_in,
                              void* d_out, int out_size, void* d_ws, size_t ws_size,
                              hipStream_t stream)
{
    (void)in_sizes; (void)n_in; (void)out_size; (void)ws_size;
    const float* query = (const float*)d_in[2];
    const float* s0    = (const float*)d_in[3];
    const float* s1    = (const float*)d_in[4];
    const float* sr0   = (const float*)d_in[5];
    const float* sr1   = (const float*)d_in[6];
    const float* Mrg   = (const float*)d_in[7];
    const float* Mor   = (const float*)d_in[8];
    const float* D_S   = (const float*)d_in[9];
    const float* Wc1   = (const float*)d_in[10];
    const float* bc1   = (const float*)d_in[11];
    const float* Wc11  = (const float*)d_in[12];
    const float* bc11  = (const float*)d_in[13];
    const float* Wg    = (const float*)d_in[14];
    const float* bg    = (const float*)d_in[15];
    const float* Wem   = (const float*)d_in[16];
    const float* bem   = (const float*)d_in[17];
    const float* Wq    = (const float*)d_in[18];
    const float* Wk    = (const float*)d_in[19];
    const float* Wv    = (const float*)d_in[20];
    const float* Wfc   = (const float*)d_in[21];
    const float* bfc   = (const float*)d_in[22];
    const float* ln1w  = (const float*)d_in[23];
    const float* ln1b  = (const float*)d_in[24];
    const float* ln2w  = (const float*)d_in[25];
    const float* ln2b  = (const float*)d_in[26];
    const float* Wff1  = (const float*)d_in[27];
    const float* bff1  = (const float*)d_in[28];
    const float* Wff2  = (const float*)d_in[29];
    const float* bff2  = (const float*)d_in[30];
    const float* Wfs   = (const float*)d_in[31];
    const float* bfs   = (const float*)d_in[32];
    const float* Wfg   = (const float*)d_in[33];
    const float* bfg   = (const float*)d_in[34];

    float* ws = (float*)d_ws;
    size_t off = 0;
    auto alloc = [&](size_t n) { float* p = ws + off; off += n; return p; };
    float* q_buf = alloc(4915200);   // (B,N,T,E)
    float* Xc    = alloc(4915200);   // (B,N,T,E) -- doubles as qq pre-CHGCN
    float* x_buf = alloc(4915200);   // doubles as attnO (in-place A1)
    float* US    = alloc(4915200);   // doubles as vv pre-A2
    float* ho    = alloc(2457600);   // (B,C,N,T)
    float* t0    = alloc(2457600);
    float* t1    = alloc(2457600);   // t0+t1 contiguous: doubles as kk
    float* xr    = alloc(393216);    // (B,C,R,T)
    float* tr0   = alloc(393216);
    float* tr1   = alloc(393216);
    float* hr    = alloc(393216);
    float* xsg   = alloc(98304);     // (B,C,G,T)
    float* tg0   = alloc(98304);
    float* tg1   = alloc(98304);
    float* xg0   = alloc(98304);
    float* dsb   = alloc(25600);     // (N,E)
    float* Ag    = alloc(256);
    float* sg0   = alloc(256);
    float* sg1   = alloc(256);

    float* qq    = Xc;               // live only during [k_qkv, k_attn3]
    float* kk    = t0;               // (contiguous with t1)
    float* vv    = US;
    float* attnO = x_buf;

    float* out_main = (float*)d_out;          // (B,C,N,T)
    float* out_xc   = out_main + 2457600;     // (B,C,R,T) final hr
    float* out_xs   = out_main + 2850816;     // (B,C,G,T) final xg

    hipFuncSetAttribute((const void*)k_attn3,
                        hipFuncAttributeMaxDynamicSharedMemorySize, 159872);
    hipFuncSetAttribute((const void*)k_A2n,
                        hipFuncAttributeMaxDynamicSharedMemorySize, 148736);
    hipFuncSetAttribute((const void*)k_A3n,
                        hipFuncAttributeMaxDynamicSharedMemorySize, 75008);

    hipMemsetAsync(Ag, 0, 256 * sizeof(float), stream);

    // ---- Transformer front (before CHGCN so qq/kk/vv can alias Xc/t0t1/US)
    k_ds<<<400, 64, 0, stream>>>(D_S, Wem, bem, dsb);
    k_conv1<<<800, 256, 0, stream>>>(query, Wc1, bc1, dsb, q_buf);
    k_qkv<<<dim3(384, 7), 256, 0, stream>>>(q_buf, Wq, Wk, Wv, qq, kk, vv);
    k_attn3<<<768, 1024, 159872, stream>>>(qq, kk, vv, attnO);
    k_A1n<<<1200, 256, 0, stream>>>(attnO, Wfc, bfc, q_buf, ln1w, ln1b, x_buf);
    k_A2n<<<1200, 512, 148736, stream>>>(x_buf, Wff1, bff1, Wff2, bff2,
                                         ln2w, ln2b, US);

    // ---- CHGCN ----
    k_spatial<<<dim3(512, 4), 256, 0, stream>>>(s0, 1, 400, 400, query, nullptr, 1.f, 0, t0);
    k_spatial<<<dim3(512, 4), 256, 0, stream>>>(s1, 1, 400, 400, query, nullptr, 1.f, 0, t1);
    k_gcn_combine<<<800, 256, 0, stream>>>(query, t0, t1, Wg, bg, 400, ho);
    k_spatial<<<dim3(512, 1), 256, 0, stream>>>(Mor, 1, 400, 64, query, nullptr, 1.f, 0, xr);
    k_spatial<<<dim3(512, 1), 256, 0, stream>>>(sr0, 1, 64, 64, xr, nullptr, 1.f, 0, tr0);
    k_spatial<<<dim3(512, 1), 256, 0, stream>>>(sr1, 1, 64, 64, xr, nullptr, 1.f, 0, tr1);
    k_gcn_combine<<<128, 256, 0, stream>>>(xr, tr0, tr1, Wg, bg, 64, hr);
    k_spatial<<<dim3(512, 1), 256, 0, stream>>>(Mrg, 1, 64, 16, xr, nullptr, 1.f, 0, xsg);
    k_agp<<<24, 256, 0, stream>>>(xsg, Ag);
    k_agf<<<1, 64, 0, stream>>>(Ag, sg0, sg1);
    k_spatial<<<dim3(512, 1), 256, 0, stream>>>(sg0, 1, 16, 16, xsg, nullptr, 1.f, 0, tg0);
    k_spatial<<<dim3(512, 1), 256, 0, stream>>>(sg1, 1, 16, 16, xsg, nullptr, 1.f, 0, tg1);
    k_gcn_combine<<<32, 256, 0, stream>>>(xsg, tg0, tg1, Wg, bg, 16, xg0);
    k_spatial<<<dim3(512, 1), 256, 0, stream>>>(Mrg, 0, 16, 64, xg0, hr, 0.5f, 1, hr);
    k_spatial<<<dim3(512, 4), 256, 0, stream>>>(Mor, 0, 64, 400, hr, ho, 0.5f, 1, ho);
    k_spatial<<<dim3(512, 1), 256, 0, stream>>>(Mor, 1, 400, 64, ho, hr, 0.5f, 1, out_xc);
    k_spatial<<<dim3(512, 1), 256, 0, stream>>>(Mrg, 1, 64, 16, out_xc, xg0, 0.5f, 1, out_xs);

    // ---- Tail ----
    k_conv1<<<800, 256, 0, stream>>>(ho, Wc1, bc1, nullptr, Xc);
    k_A3n<<<1200, 256, 75008, stream>>>(US, Xc, Wfs, bfs, Wfg, bfg, Wc11, bc11, out_main);
}